// Round 3
// baseline (5373.811 us; speedup 1.0000x reference)
//
#include <hip/hip_runtime.h>
#include <math.h>

#define LSEQ 384
#define HD 256
#define PDIM 64
#define NHEAD 4
#define NBINS 65
#define BATCH 2

// ---- DPP-based wave64 reductions (VALU pipe, not LDS) ----
template<int CTRL, int RMASK>
__device__ __forceinline__ float dpp_sum_step(float v) {
    int x = __builtin_amdgcn_update_dpp(0, __float_as_int(v), CTRL, RMASK, 0xf, true);
    return v + __int_as_float(x);
}
template<int CTRL, int RMASK>
__device__ __forceinline__ float dpp_max_step(float v) {
    int x = __builtin_amdgcn_update_dpp(__float_as_int(v), __float_as_int(v), CTRL, RMASK, 0xf, false);
    return fmaxf(v, __int_as_float(x));
}
__device__ __forceinline__ float wsum(float v) {
    v = dpp_sum_step<0x111, 0xf>(v);   // row_shr:1
    v = dpp_sum_step<0x112, 0xf>(v);   // row_shr:2
    v = dpp_sum_step<0x114, 0xf>(v);   // row_shr:4
    v = dpp_sum_step<0x118, 0xf>(v);   // row_shr:8
    v = dpp_sum_step<0x142, 0xa>(v);   // row_bcast:15 into rows 1,3
    v = dpp_sum_step<0x143, 0xc>(v);   // row_bcast:31 into rows 2,3
    return __int_as_float(__builtin_amdgcn_readlane(__float_as_int(v), 63));
}
__device__ __forceinline__ float wmax(float v) {
    v = dpp_max_step<0x111, 0xf>(v);
    v = dpp_max_step<0x112, 0xf>(v);
    v = dpp_max_step<0x114, 0xf>(v);
    v = dpp_max_step<0x118, 0xf>(v);
    v = dpp_max_step<0x142, 0xa>(v);
    v = dpp_max_step<0x143, 0xc>(v);
    return __int_as_float(__builtin_amdgcn_readlane(__float_as_int(v), 63));
}
__device__ __forceinline__ float gelu_erf(float x) {
    return 0.5f * x * (1.0f + erff(x * 0.70710678f));
}

// h[b,l,:] = x[b,l,:] @ rp_w + rp_b + pos[l,:]
__global__ void k_h_init(const float* __restrict__ x, const float* __restrict__ rp_w,
                         const float* __restrict__ rp_b, const float* __restrict__ pos,
                         float* __restrict__ h) {
    __shared__ float xs[48];
    int row = blockIdx.x;            // b*L + l
    int l = row % LSEQ;
    int t = threadIdx.x;
    if (t < 48) xs[t] = x[row * 48 + t];
    __syncthreads();
    float acc = rp_b[t] + pos[l * HD + t];
#pragma unroll 8
    for (int a = 0; a < 48; ++a) acc += xs[a] * rp_w[a * HD + t];
    h[row * HD + t] = acc;
}

// pA[row,:] = h[row,:] @ wA (+ bA);  pB[row,:] = h[row,:] @ wB (+ bB)
// center!=0: subtract per-row mean from each projection (for LN-mean elimination)
__global__ void k_proj2(const float* __restrict__ h, const float* __restrict__ wA,
                        const float* __restrict__ wB, const float* __restrict__ bA,
                        const float* __restrict__ bB, int center,
                        float* __restrict__ pA, float* __restrict__ pB) {
    __shared__ float hs[HD];
    int row = blockIdx.x;
    int t = threadIdx.x;
    hs[t] = h[row * HD + t];
    hs[t + 128] = h[row * HD + t + 128];
    __syncthreads();
    int col = t & 63;
    const float* w = (t < 64) ? wA : wB;
    const float* bias = (t < 64) ? bA : bB;
    float acc = bias ? bias[col] : 0.0f;
#pragma unroll 8
    for (int a = 0; a < HD; ++a) acc += hs[a] * w[a * PDIM + col];
    if (center) {
        float mean = wsum(acc) * (1.0f / PDIM);
        acc -= mean;
    }
    float* p = (t < 64) ? pA : pB;
    p[row * PDIM + col] = acc;
}

// pair[b,i,j,:] = pi[b,i,:] + pj[b,j,:] + rel_emb[clip(j-i)+32,:]
__global__ void k_pair_init(const float* __restrict__ pi, const float* __restrict__ pj,
                            const float* __restrict__ rel_emb, float* __restrict__ pair) {
    __shared__ float pis[PDIM];
    int row = blockIdx.x;            // b*L + i
    int b = row / LSEQ, i = row % LSEQ;
    int t = threadIdx.x;
    if (t < PDIM) pis[t] = pi[row * PDIM + t];
    __syncthreads();
    const float* pjb = pj + (size_t)b * LSEQ * PDIM;
    float* pr = pair + (size_t)row * LSEQ * PDIM;
    for (int n = t; n < LSEQ * PDIM; n += 256) {
        int j = n >> 6, d = n & 63;
        int r = j - i; r = r < -32 ? -32 : (r > 32 ? 32 : r); r += 32;
        pr[n] = pis[d] + pjb[j * PDIM + d] + rel_emb[r * PDIM + d];
    }
}

// prep: fold LN gamma/beta into first-layer weights for pair-update MLPs + dist head.
// i<4: w1p[i] = pu_ln_g[i] (.) pu_w1[i];  b1p[i] = pu_b1[i] + pu_ln_b[i] @ pu_w1[i]
// i==4: same for dh_*; also repack dh_w2 (64x65) into w2p (64x64) + w2c (col 64)
__global__ void k_prep(const float* __restrict__ pu_ln_g, const float* __restrict__ pu_ln_b,
                       const float* __restrict__ pu_w1, const float* __restrict__ pu_b1,
                       const float* __restrict__ dh_ln_g, const float* __restrict__ dh_ln_b,
                       const float* __restrict__ dh_w1, const float* __restrict__ dh_b1,
                       const float* __restrict__ dh_w2,
                       float* __restrict__ w1p, float* __restrict__ b1p,
                       float* __restrict__ w2p, float* __restrict__ w2c) {
    int i = blockIdx.x;              // 0..4
    int t = threadIdx.x;             // 0..63
    const float *g, *bb, *w1, *b1;
    if (i < 4) { g = pu_ln_g + i * 64; bb = pu_ln_b + i * 64; w1 = pu_w1 + i * 4096; b1 = pu_b1 + i * 64; }
    else       { g = dh_ln_g;          bb = dh_ln_b;          w1 = dh_w1;            b1 = dh_b1; }
    float accb = b1[t];
    for (int k = 0; k < 64; ++k) {
        float wv = w1[k * 64 + t];
        w1p[i * 4096 + k * 64 + t] = g[k] * wv;
        accb += bb[k] * wv;
    }
    b1p[i * 64 + t] = accb;
    if (i == 4) {
        for (int c = 0; c < 64; ++c) w2p[c * 64 + t] = dh_w2[c * 65 + t];
        w2c[t] = dh_w2[t * 65 + 64];
    }
}

// mask[l,m] = (1/(B*NH)) * sum_b LN(pair[b,l,m,:]) . pbsum
__global__ void k_mask(const float* __restrict__ pair, const float* __restrict__ g,
                       const float* __restrict__ bb, const float* __restrict__ pbw,
                       float* __restrict__ mask) {
    int wid = (blockIdx.x * 4 + (threadIdx.x >> 6)) * 2;
    int lane = threadIdx.x & 63;
    int l = wid / LSEQ, m0 = wid % LSEQ;
    float gd = g[lane], bd = bb[lane];
    float pbs = pbw[lane * 4] + pbw[lane * 4 + 1] + pbw[lane * 4 + 2] + pbw[lane * 4 + 3];
    float v[4];
#pragma unroll
    for (int s = 0; s < 4; ++s) {
        int b = s >> 1, m = m0 + (s & 1);
        v[s] = pair[(((size_t)(b * LSEQ + l)) * LSEQ + m) * PDIM + lane];
    }
    float mean[4], d[4], var[4], dot[4];
#pragma unroll
    for (int s = 0; s < 4; ++s) mean[s] = wsum(v[s]) * (1.0f / PDIM);
#pragma unroll
    for (int s = 0; s < 4; ++s) d[s] = v[s] - mean[s];
#pragma unroll
    for (int s = 0; s < 4; ++s) var[s] = wsum(d[s] * d[s]) * (1.0f / PDIM);
#pragma unroll
    for (int s = 0; s < 4; ++s) {
        float ln = d[s] * rsqrtf(var[s] + 1e-5f) * gd + bd;
        dot[s] = wsum(ln * pbs);
    }
    if (lane == 0) {
        mask[l * LSEQ + m0]     = (dot[0] + dot[2]) * (1.0f / (BATCH * NHEAD));
        mask[l * LSEQ + m0 + 1] = (dot[1] + dot[3]) * (1.0f / (BATCH * NHEAD));
    }
}

// seq layernorm: one row per block
__global__ void k_ln_seq(const float* __restrict__ h, const float* __restrict__ g,
                         const float* __restrict__ b, float* __restrict__ out) {
    __shared__ float red[8];
    int row = blockIdx.x;
    int t = threadIdx.x;
    int w = t >> 6, lane = t & 63;
    float v = h[row * HD + t];
    float s = wsum(v);
    if (lane == 0) red[w] = s;
    __syncthreads();
    float mean = (red[0] + red[1] + red[2] + red[3]) * (1.0f / HD);
    float d = v - mean;
    float q = wsum(d * d);
    if (lane == 0) red[4 + w] = q;
    __syncthreads();
    float var = (red[4] + red[5] + red[6] + red[7]) * (1.0f / HD);
    out[row * HD + t] = d * rsqrtf(var + 1e-5f) * g[t] + b[t];
}

// qkv = seq_n @ in_w + in_b ; 8 rows per block
__global__ void k_qkv(const float* __restrict__ sn, const float* __restrict__ w,
                      const float* __restrict__ bias, float* __restrict__ qkv) {
    __shared__ float xs[8][HD];
    int r0 = blockIdx.x * 8;
    int t = threadIdx.x;
#pragma unroll
    for (int r = 0; r < 8; ++r) xs[r][t] = sn[(r0 + r) * HD + t];
    __syncthreads();
#pragma unroll
    for (int c = 0; c < 3; ++c) {
        int j = c * HD + t;
        float acc[8];
#pragma unroll
        for (int r = 0; r < 8; ++r) acc[r] = 0.0f;
        for (int a = 0; a < HD; ++a) {
            float wv = w[a * 768 + j];
#pragma unroll
            for (int r = 0; r < 8; ++r) acc[r] += xs[r][a] * wv;
        }
        float bv = bias[j];
#pragma unroll
        for (int r = 0; r < 8; ++r) qkv[(r0 + r) * 768 + j] = acc[r] + bv;
    }
}

// attention for one (b, nh, l) per block
__global__ void k_attn(const float* __restrict__ qkv, const float* __restrict__ mask,
                       float* __restrict__ o) {
    __shared__ __align__(16) float qs[64];
    __shared__ float sc[LSEQ];
    __shared__ float red[8];
    __shared__ float op[4][64];
    int bid = blockIdx.x;
    int l = bid % LSEQ;
    int nh = (bid / LSEQ) & 3;
    int b = bid / (LSEQ * NHEAD);
    int t = threadIdx.x;
    int w = t >> 6, lane = t & 63;
    const float* qbase = qkv + ((size_t)(b * LSEQ + l)) * 768 + nh * 64;
    if (t < 64) qs[t] = qbase[t];
    __syncthreads();
    float lmax = -1e30f;
    float myv[2];
#pragma unroll
    for (int it = 0; it < 2; ++it) {
        int m = t + it * 256;
        if (m < LSEQ) {
            const float* kb = qkv + ((size_t)(b * LSEQ + m)) * 768 + 256 + nh * 64;
            const float4* k4 = (const float4*)kb;
            const float4* q4 = (const float4*)qs;
            float acc = 0.0f;
#pragma unroll
            for (int a = 0; a < 16; ++a) {
                float4 kv = k4[a], qv = q4[a];
                acc += qv.x * kv.x + qv.y * kv.y + qv.z * kv.z + qv.w * kv.w;
            }
            float s = acc * 0.125f + mask[l * LSEQ + m];
            myv[it] = s;
            lmax = fmaxf(lmax, s);
        } else myv[it] = -1e30f;
    }
    float wm = wmax(lmax);
    if (lane == 0) red[w] = wm;
    __syncthreads();
    float gmax = fmaxf(fmaxf(red[0], red[1]), fmaxf(red[2], red[3]));
    float lsum = 0.0f;
#pragma unroll
    for (int it = 0; it < 2; ++it) {
        int m = t + it * 256;
        if (m < LSEQ) {
            float e = expf(myv[it] - gmax);
            sc[m] = e;
            lsum += e;
        }
    }
    float ws = wsum(lsum);
    if (lane == 0) red[4 + w] = ws;
    __syncthreads();
    float inv = 1.0f / (red[4] + red[5] + red[6] + red[7]);
    int d = t & 63, gq = t >> 6;
    float part = 0.0f;
    for (int m = gq * 96; m < (gq + 1) * 96; ++m)
        part += sc[m] * qkv[((size_t)(b * LSEQ + m)) * 768 + 512 + nh * 64 + d];
    op[gq][d] = part;
    __syncthreads();
    if (t < 64) {
        float ov = (op[0][t] + op[1][t] + op[2][t] + op[3][t]) * inv;
        o[((size_t)(b * LSEQ + l)) * HD + nh * 64 + t] = ov;
    }
}

// h += o @ out_w + out_b ; 8 rows per block
__global__ void k_outproj(const float* __restrict__ o, const float* __restrict__ w,
                          const float* __restrict__ bias, float* __restrict__ h) {
    __shared__ float os[8][HD];
    int r0 = blockIdx.x * 8;
    int t = threadIdx.x;
#pragma unroll
    for (int r = 0; r < 8; ++r) os[r][t] = o[(r0 + r) * HD + t];
    __syncthreads();
    float acc[8] = {};
    for (int a = 0; a < HD; ++a) {
        float wv = w[a * HD + t];
#pragma unroll
        for (int r = 0; r < 8; ++r) acc[r] += os[r][a] * wv;
    }
    float bv = bias[t];
#pragma unroll
    for (int r = 0; r < 8; ++r) h[(r0 + r) * HD + t] += acc[r] + bv;
}

// mid = gelu(LN(h) @ ff_w1 + b1) ; 8 rows per block
__global__ void k_ff1(const float* __restrict__ h, const float* __restrict__ g,
                      const float* __restrict__ bb, const float* __restrict__ w,
                      const float* __restrict__ b1, float* __restrict__ mid) {
    __shared__ float hs[8][HD];
    __shared__ float red[8];
    int r0 = blockIdx.x * 8;
    int t = threadIdx.x;
    int wv_ = t >> 6, lane = t & 63;
#pragma unroll
    for (int r = 0; r < 8; ++r) hs[r][t] = h[(r0 + r) * HD + t];
    __syncthreads();
    float gt = g[t], bt = bb[t];
    for (int r = 0; r < 8; ++r) {
        float v = hs[r][t];
        float s = wsum(v);
        if (lane == 0) red[wv_] = s;
        __syncthreads();
        float mean = (red[0] + red[1] + red[2] + red[3]) * (1.0f / HD);
        float d = v - mean;
        float q = wsum(d * d);
        if (lane == 0) red[4 + wv_] = q;
        __syncthreads();
        float var = (red[4] + red[5] + red[6] + red[7]) * (1.0f / HD);
        hs[r][t] = d * rsqrtf(var + 1e-5f) * gt + bt;
        __syncthreads();
    }
#pragma unroll
    for (int c = 0; c < 4; ++c) {
        int j = c * HD + t;
        float acc[8] = {};
        for (int a = 0; a < HD; ++a) {
            float wv = w[a * 1024 + j];
#pragma unroll
            for (int r = 0; r < 8; ++r) acc[r] += hs[r][a] * wv;
        }
        float bv = b1[j];
#pragma unroll
        for (int r = 0; r < 8; ++r) mid[(r0 + r) * 1024 + j] = gelu_erf(acc[r] + bv);
    }
}

// h += mid @ ff_w2 + b2 ; 8 rows per block
__global__ void k_ff2(const float* __restrict__ mid, const float* __restrict__ w,
                      const float* __restrict__ b2, float* __restrict__ h) {
    __shared__ float ms[8 * 1024];
    int r0 = blockIdx.x * 8;
    int t = threadIdx.x;
    for (int n = t; n < 8192; n += 256) ms[n] = mid[r0 * 1024 + n];
    __syncthreads();
    float acc[8] = {};
    for (int a = 0; a < 1024; ++a) {
        float wv = w[a * HD + t];
#pragma unroll
        for (int r = 0; r < 8; ++r) acc[r] += ms[r * 1024 + a] * wv;
    }
    float bv = b2[t];
#pragma unroll
    for (int r = 0; r < 8; ++r) h[(r0 + r) * HD + t] += acc[r] + bv;
}

// pair[b,l,m,:] += gelu(z @ W1' + b1') @ w2 + b2, z = centered(oi+oj)*rsqrt(var)
// lane = m. Activations per-lane in VGPRs; weights fetched as wave-uniform
// s_loads (scalar pipe); LN serial in registers (inputs pre-centered). No LDS.
__global__ void __launch_bounds__(64, 3) k_pair_upd(
    const float* __restrict__ ojc,   // centered oj        (B,L,64)
    const float* __restrict__ oic,   // centered oi+outer_b (B,L,64)
    const float* __restrict__ w1p,   // g-folded W1 (64,64)
    const float* __restrict__ b1p,   // folded b1   (64)
    const float* __restrict__ w2,    // pu_w2 (64,64)
    const float* __restrict__ b2,    // pu_b2 (64)
    float* __restrict__ pair) {
    int blk = blockIdx.x;            // (b*L + l)*6 + chunk
    int row = blk / 6, chunk = blk % 6;
    int b = row / LSEQ;
    int m = chunk * 64 + threadIdx.x;
    const float4* oj4 = (const float4*)(ojc + ((size_t)b * LSEQ + m) * 64);
    const float* oir = oic + (size_t)row * 64;   // lane-uniform
    float v[64];
#pragma unroll
    for (int j = 0; j < 16; ++j) {
        float4 tv = oj4[j];
        v[4 * j] = tv.x; v[4 * j + 1] = tv.y; v[4 * j + 2] = tv.z; v[4 * j + 3] = tv.w;
    }
#pragma unroll
    for (int k = 0; k < 64; ++k) v[k] += oir[k];           // s_load + v_add
    float ss = 0.0f;
#pragma unroll
    for (int k = 0; k < 64; ++k) ss = fmaf(v[k], v[k], ss); // mean==0 by pre-centering
    float rs = rsqrtf(ss * (1.0f / PDIM) + 1e-5f);
#pragma unroll
    for (int k = 0; k < 64; ++k) v[k] *= rs;
    float acc[64];
#pragma unroll
    for (int c = 0; c < 64; ++c) acc[c] = b1p[c];
#pragma unroll
    for (int k = 0; k < 64; ++k) {
        float zk = v[k];
#pragma unroll
        for (int c = 0; c < 64; ++c) acc[c] = fmaf(w1p[k * 64 + c], zk, acc[c]);
    }
#pragma unroll
    for (int c = 0; c < 64; ++c) v[c] = gelu_erf(acc[c]);   // u, reuse v
#pragma unroll
    for (int e = 0; e < 64; ++e) acc[e] = b2[e];
#pragma unroll
    for (int c = 0; c < 64; ++c) {
        float uc = v[c];
#pragma unroll
        for (int e = 0; e < 64; ++e) acc[e] = fmaf(w2[c * 64 + e], uc, acc[e]);
    }
    float4* pr4 = (float4*)(pair + ((size_t)row * LSEQ + m) * 64);
#pragma unroll
    for (int j = 0; j < 16; ++j) {
        float4 tv = pr4[j];
        tv.x += acc[4 * j]; tv.y += acc[4 * j + 1];
        tv.z += acc[4 * j + 2]; tv.w += acc[4 * j + 3];
        pr4[j] = tv;
    }
}

// logits = gelu(LN(pair) @ dhW1' + b1') @ dh_w2 + dh_b2 ; lane = m, same scheme
__global__ void __launch_bounds__(64, 3) k_dist(
    const float* __restrict__ pair, const float* __restrict__ w1p,
    const float* __restrict__ b1p, const float* __restrict__ w2p,
    const float* __restrict__ w2c, const float* __restrict__ b2,
    float* __restrict__ out) {
    int blk = blockIdx.x;
    int row = blk / 6, chunk = blk % 6;
    int m = chunk * 64 + threadIdx.x;
    const float4* pr4 = (const float4*)(pair + ((size_t)row * LSEQ + m) * 64);
    float v[64];
#pragma unroll
    for (int j = 0; j < 16; ++j) {
        float4 tv = pr4[j];
        v[4 * j] = tv.x; v[4 * j + 1] = tv.y; v[4 * j + 2] = tv.z; v[4 * j + 3] = tv.w;
    }
    float s = 0.0f;
#pragma unroll
    for (int k = 0; k < 64; ++k) s += v[k];
    float mean = s * (1.0f / PDIM);
    float ss = 0.0f;
#pragma unroll
    for (int k = 0; k < 64; ++k) { float d = v[k] - mean; v[k] = d; ss = fmaf(d, d, ss); }
    float rs = rsqrtf(ss * (1.0f / PDIM) + 1e-5f);
#pragma unroll
    for (int k = 0; k < 64; ++k) v[k] *= rs;
    float acc[64];
#pragma unroll
    for (int c = 0; c < 64; ++c) acc[c] = b1p[c];
#pragma unroll
    for (int k = 0; k < 64; ++k) {
        float zk = v[k];
#pragma unroll
        for (int c = 0; c < 64; ++c) acc[c] = fmaf(w1p[k * 64 + c], zk, acc[c]);
    }
#pragma unroll
    for (int c = 0; c < 64; ++c) v[c] = gelu_erf(acc[c]);
    float c64 = b2[64];
#pragma unroll
    for (int c = 0; c < 64; ++c) c64 = fmaf(w2c[c], v[c], c64);
#pragma unroll
    for (int e = 0; e < 64; ++e) acc[e] = b2[e];
#pragma unroll
    for (int c = 0; c < 64; ++c) {
        float uc = v[c];
#pragma unroll
        for (int e = 0; e < 64; ++e) acc[e] = fmaf(w2p[c * 64 + e], uc, acc[e]);
    }
    float* orow = out + ((size_t)row * LSEQ + m) * NBINS;
#pragma unroll
    for (int e = 0; e < 64; ++e) orow[e] = acc[e];
    orow[64] = c64;
}

// out = (out + out^T(1,2)) / 2, in place
__global__ void k_sym(float* __restrict__ out) {
    int row = blockIdx.x;            // b*L + l
    int b = row / LSEQ, l = row % LSEQ;
    int t = threadIdx.x;
    float* obp = out + (size_t)b * LSEQ * LSEQ * NBINS;
    int tot = (LSEQ - l) * NBINS;
    for (int n = t; n < tot; n += 256) {
        int m = l + n / NBINS;
        int k = n % NBINS;
        size_t i1 = ((size_t)l * LSEQ + m) * NBINS + k;
        size_t i2 = ((size_t)m * LSEQ + l) * NBINS + k;
        float a = obp[i1], c = obp[i2];
        float vv = 0.5f * (a + c);
        obp[i1] = vv;
        obp[i2] = vv;
    }
}

extern "C" void kernel_launch(void* const* d_in, const int* in_sizes, int n_in,
                              void* d_out, int out_size, void* d_ws, size_t ws_size,
                              hipStream_t stream) {
    const float* x        = (const float*)d_in[0];
    const float* rp_w     = (const float*)d_in[1];
    const float* rp_b     = (const float*)d_in[2];
    const float* pos      = (const float*)d_in[3];
    const float* pii_w    = (const float*)d_in[4];
    const float* pii_b    = (const float*)d_in[5];
    const float* pij_w    = (const float*)d_in[6];
    const float* pij_b    = (const float*)d_in[7];
    const float* rel_emb  = (const float*)d_in[8];
    const float* ln_seq_g = (const float*)d_in[9];
    const float* ln_seq_b = (const float*)d_in[10];
    const float* ln_pair_g= (const float*)d_in[11];
    const float* ln_pair_b= (const float*)d_in[12];
    const float* pb_w     = (const float*)d_in[13];
    const float* in_w     = (const float*)d_in[14];
    const float* in_b     = (const float*)d_in[15];
    const float* out_w    = (const float*)d_in[16];
    const float* out_b    = (const float*)d_in[17];
    const float* ff_ln_g  = (const float*)d_in[18];
    const float* ff_ln_b  = (const float*)d_in[19];
    const float* ff_w1    = (const float*)d_in[20];
    const float* ff_b1    = (const float*)d_in[21];
    const float* ff_w2    = (const float*)d_in[22];
    const float* ff_b2    = (const float*)d_in[23];
    const float* pu_ln_g  = (const float*)d_in[24];
    const float* pu_ln_b  = (const float*)d_in[25];
    const float* pu_w1    = (const float*)d_in[26];
    const float* pu_b1    = (const float*)d_in[27];
    const float* pu_w2    = (const float*)d_in[28];
    const float* pu_b2    = (const float*)d_in[29];
    const float* outer_w  = (const float*)d_in[30];
    const float* outer_b  = (const float*)d_in[31];
    const float* dh_ln_g  = (const float*)d_in[32];
    const float* dh_ln_b  = (const float*)d_in[33];
    const float* dh_w1    = (const float*)d_in[34];
    const float* dh_b1    = (const float*)d_in[35];
    const float* dh_w2    = (const float*)d_in[36];
    const float* dh_b2    = (const float*)d_in[37];
    float* outp = (float*)d_out;

    float* W = (float*)d_ws;
    float* h    = W;  W += BATCH * LSEQ * HD;
    float* sn   = W;  W += BATCH * LSEQ * HD;
    float* qkv  = W;  W += BATCH * LSEQ * 3 * HD;
    float* ob   = W;  W += BATCH * LSEQ * HD;
    float* mid  = W;  W += BATCH * LSEQ * 4 * HD;
    float* mask = W;  W += LSEQ * LSEQ;
    float* poi  = W;  W += BATCH * LSEQ * PDIM;
    float* poj  = W;  W += BATCH * LSEQ * PDIM;
    float* w1p  = W;  W += 5 * 4096;
    float* b1p  = W;  W += 5 * 64;
    float* w2p  = W;  W += 4096;
    float* w2c  = W;  W += 64;
    float* pair = W;  W += (size_t)BATCH * LSEQ * LSEQ * PDIM;

    const int rows = BATCH * LSEQ;   // 768

    k_prep<<<5, 64, 0, stream>>>(pu_ln_g, pu_ln_b, pu_w1, pu_b1,
                                 dh_ln_g, dh_ln_b, dh_w1, dh_b1, dh_w2,
                                 w1p, b1p, w2p, w2c);
    k_h_init<<<rows, 256, 0, stream>>>(x, rp_w, rp_b, pos, h);
    k_proj2<<<rows, 128, 0, stream>>>(h, pii_w, pij_w, pii_b, pij_b, 0, poi, poj);
    k_pair_init<<<rows, 256, 0, stream>>>(poi, poj, rel_emb, pair);

    for (int i = 0; i < 4; ++i) {
        k_ln_seq<<<rows, 256, 0, stream>>>(h, ln_seq_g + i * HD, ln_seq_b + i * HD, sn);
        k_mask<<<LSEQ * LSEQ / 8, 256, 0, stream>>>(pair, ln_pair_g + i * PDIM,
                                                    ln_pair_b + i * PDIM,
                                                    pb_w + i * PDIM * NHEAD, mask);
        k_qkv<<<rows / 8, 256, 0, stream>>>(sn, in_w + i * HD * 3 * HD, in_b + i * 3 * HD, qkv);
        k_attn<<<BATCH * NHEAD * LSEQ, 256, 0, stream>>>(qkv, mask, ob);
        k_outproj<<<rows / 8, 256, 0, stream>>>(ob, out_w + i * HD * HD, out_b + i * HD, h);
        k_ff1<<<rows / 8, 256, 0, stream>>>(h, ff_ln_g + i * HD, ff_ln_b + i * HD,
                                            ff_w1 + i * HD * 4 * HD, ff_b1 + i * 4 * HD, mid);
        k_ff2<<<rows / 8, 256, 0, stream>>>(mid, ff_w2 + i * 4 * HD * HD, ff_b2 + i * HD, h);
        // centered oi+outer_b (poi) and centered oj (poj)
        k_proj2<<<rows, 128, 0, stream>>>(h, outer_w + i * 2 * HD * PDIM,
                                          outer_w + i * 2 * HD * PDIM + HD * PDIM,
                                          outer_b + i * PDIM, nullptr, 1, poi, poj);
        k_pair_upd<<<rows * 6, 64, 0, stream>>>(poj, poi,
                                                w1p + i * 4096, b1p + i * 64,
                                                pu_w2 + i * PDIM * PDIM, pu_b2 + i * PDIM, pair);
    }

    k_dist<<<rows * 6, 64, 0, stream>>>(pair, w1p + 4 * 4096, b1p + 4 * 64,
                                        w2p, w2c, dh_b2, outp);
    k_sym<<<rows, 256, 0, stream>>>(outp);
}

// Round 4
// 2013.582 us; speedup vs baseline: 2.6688x; 2.6688x over previous
//
#include <hip/hip_runtime.h>
#include <math.h>

#define LSEQ 384
#define HD 256
#define PDIM 64
#define NHEAD 4
#define NBINS 65
#define BATCH 2

typedef __attribute__((ext_vector_type(8))) short bf16x8;
typedef __attribute__((ext_vector_type(16))) float f32x16;
#define MFMA32(a, b, c) __builtin_amdgcn_mfma_f32_32x32x16_bf16(a, b, c, 0, 0, 0)

// ---- DPP-based wave64 reductions (VALU pipe, not LDS) ----
template<int CTRL, int RMASK>
__device__ __forceinline__ float dpp_sum_step(float v) {
    int x = __builtin_amdgcn_update_dpp(0, __float_as_int(v), CTRL, RMASK, 0xf, true);
    return v + __int_as_float(x);
}
template<int CTRL, int RMASK>
__device__ __forceinline__ float dpp_max_step(float v) {
    int x = __builtin_amdgcn_update_dpp(__float_as_int(v), __float_as_int(v), CTRL, RMASK, 0xf, false);
    return fmaxf(v, __int_as_float(x));
}
__device__ __forceinline__ float wsum(float v) {
    v = dpp_sum_step<0x111, 0xf>(v);
    v = dpp_sum_step<0x112, 0xf>(v);
    v = dpp_sum_step<0x114, 0xf>(v);
    v = dpp_sum_step<0x118, 0xf>(v);
    v = dpp_sum_step<0x142, 0xa>(v);
    v = dpp_sum_step<0x143, 0xc>(v);
    return __int_as_float(__builtin_amdgcn_readlane(__float_as_int(v), 63));
}
__device__ __forceinline__ float wmax(float v) {
    v = dpp_max_step<0x111, 0xf>(v);
    v = dpp_max_step<0x112, 0xf>(v);
    v = dpp_max_step<0x114, 0xf>(v);
    v = dpp_max_step<0x118, 0xf>(v);
    v = dpp_max_step<0x142, 0xa>(v);
    v = dpp_max_step<0x143, 0xc>(v);
    return __int_as_float(__builtin_amdgcn_readlane(__float_as_int(v), 63));
}
__device__ __forceinline__ float gelu_erf(float x) {
    return 0.5f * x * (1.0f + erff(x * 0.70710678f));
}

// bf16 RNE conversion + error-compensated split: x ~= hi + lo
__device__ __forceinline__ unsigned short f2bf(float x) {
    unsigned u = __float_as_uint(x);
    unsigned r = (u + 0x7fff + ((u >> 16) & 1)) >> 16;
    return (unsigned short)r;
}
__device__ __forceinline__ float bf2f(unsigned short h) {
    return __uint_as_float(((unsigned)h) << 16);
}
__device__ __forceinline__ void split_bf(float x, unsigned short& h, unsigned short& l) {
    h = f2bf(x);
    l = f2bf(x - bf2f(h));
}

// h[b,l,:] = x[b,l,:] @ rp_w + rp_b + pos[l,:]
__global__ void k_h_init(const float* __restrict__ x, const float* __restrict__ rp_w,
                         const float* __restrict__ rp_b, const float* __restrict__ pos,
                         float* __restrict__ h) {
    __shared__ float xs[48];
    int row = blockIdx.x;            // b*L + l
    int l = row % LSEQ;
    int t = threadIdx.x;
    if (t < 48) xs[t] = x[row * 48 + t];
    __syncthreads();
    float acc = rp_b[t] + pos[l * HD + t];
#pragma unroll 8
    for (int a = 0; a < 48; ++a) acc += xs[a] * rp_w[a * HD + t];
    h[row * HD + t] = acc;
}

// pA[row,:] = h[row,:] @ wA (+ bA);  pB[row,:] = h[row,:] @ wB (+ bB)
// center!=0: subtract per-row mean (LN-mean elimination downstream)
__global__ void k_proj2(const float* __restrict__ h, const float* __restrict__ wA,
                        const float* __restrict__ wB, const float* __restrict__ bA,
                        const float* __restrict__ bB, int center,
                        float* __restrict__ pA, float* __restrict__ pB) {
    __shared__ float hs[HD];
    int row = blockIdx.x;
    int t = threadIdx.x;
    hs[t] = h[row * HD + t];
    hs[t + 128] = h[row * HD + t + 128];
    __syncthreads();
    int col = t & 63;
    const float* w = (t < 64) ? wA : wB;
    const float* bias = (t < 64) ? bA : bB;
    float acc = bias ? bias[col] : 0.0f;
#pragma unroll 8
    for (int a = 0; a < HD; ++a) acc += hs[a] * w[a * PDIM + col];
    if (center) {
        float mean = wsum(acc) * (1.0f / PDIM);
        acc -= mean;
    }
    float* p = (t < 64) ? pA : pB;
    p[row * PDIM + col] = acc;
}

// pair[b,i,j,:] = pi[b,i,:] + pj[b,j,:] + rel_emb[clip(j-i)+32,:]
__global__ void k_pair_init(const float* __restrict__ pi, const float* __restrict__ pj,
                            const float* __restrict__ rel_emb, float* __restrict__ pair) {
    __shared__ float pis[PDIM];
    int row = blockIdx.x;            // b*L + i
    int b = row / LSEQ, i = row % LSEQ;
    int t = threadIdx.x;
    if (t < PDIM) pis[t] = pi[row * PDIM + t];
    __syncthreads();
    const float* pjb = pj + (size_t)b * LSEQ * PDIM;
    float* pr = pair + (size_t)row * LSEQ * PDIM;
    for (int n = t; n < LSEQ * PDIM; n += 256) {
        int j = n >> 6, d = n & 63;
        int r = j - i; r = r < -32 ? -32 : (r > 32 ? 32 : r); r += 32;
        pr[n] = pis[d] + pjb[j * PDIM + d] + rel_emb[r * PDIM + d];
    }
}

// prep: fold LN g/b into W1 (b1p = b1 + bb@W1), split all pair-MLP weights into
// bf16 hi/lo, stored TRANSPOSED [out][k] for direct 16B MFMA A-frag loads.
// i<4: pair-update layer i ; i==4: dist head (also extracts dh_w2 col 64)
__global__ void k_prep(const float* __restrict__ pu_ln_g, const float* __restrict__ pu_ln_b,
                       const float* __restrict__ pu_w1, const float* __restrict__ pu_b1,
                       const float* __restrict__ pu_w2,
                       const float* __restrict__ dh_ln_g, const float* __restrict__ dh_ln_b,
                       const float* __restrict__ dh_w1, const float* __restrict__ dh_b1,
                       const float* __restrict__ dh_w2,
                       unsigned short* __restrict__ w1hT, unsigned short* __restrict__ w1lT,
                       unsigned short* __restrict__ w2hT, unsigned short* __restrict__ w2lT,
                       float* __restrict__ b1p, float* __restrict__ w2c) {
    int i = blockIdx.x;              // 0..4
    int c = threadIdx.x;             // 0..63 = output row of transposed arrays
    const float *g, *bb, *w1, *b1, *w2;
    int w2s;
    if (i < 4) { g = pu_ln_g + i * 64; bb = pu_ln_b + i * 64; w1 = pu_w1 + i * 4096;
                 b1 = pu_b1 + i * 64; w2 = pu_w2 + i * 4096; w2s = 64; }
    else       { g = dh_ln_g; bb = dh_ln_b; w1 = dh_w1; b1 = dh_b1; w2 = dh_w2; w2s = 65; }
    float accb = b1[c];
    for (int k = 0; k < 64; ++k) {
        float wv = w1[k * 64 + c];
        accb += bb[k] * wv;
        unsigned short h, l;
        split_bf(g[k] * wv, h, l);                 // W1'[k][c] stored at [c][k]
        w1hT[i * 4096 + c * 64 + k] = h;
        w1lT[i * 4096 + c * 64 + k] = l;
        split_bf(w2[k * w2s + c], h, l);           // W2[k][c] stored at [c][k]
        w2hT[i * 4096 + c * 64 + k] = h;
        w2lT[i * 4096 + c * 64 + k] = l;
    }
    b1p[i * 64 + c] = accb;
    if (i == 4) w2c[c] = dh_w2[c * 65 + 64];
}

// mask[l,m] = (1/(B*NH)) * sum_b LN(pair[b,l,m,:]) . pbsum
__global__ void k_mask(const float* __restrict__ pair, const float* __restrict__ g,
                       const float* __restrict__ bb, const float* __restrict__ pbw,
                       float* __restrict__ mask) {
    int wid = (blockIdx.x * 4 + (threadIdx.x >> 6)) * 2;
    int lane = threadIdx.x & 63;
    int l = wid / LSEQ, m0 = wid % LSEQ;
    float gd = g[lane], bd = bb[lane];
    float pbs = pbw[lane * 4] + pbw[lane * 4 + 1] + pbw[lane * 4 + 2] + pbw[lane * 4 + 3];
    float v[4];
#pragma unroll
    for (int s = 0; s < 4; ++s) {
        int b = s >> 1, m = m0 + (s & 1);
        v[s] = pair[(((size_t)(b * LSEQ + l)) * LSEQ + m) * PDIM + lane];
    }
    float mean[4], d[4], var[4], dot[4];
#pragma unroll
    for (int s = 0; s < 4; ++s) mean[s] = wsum(v[s]) * (1.0f / PDIM);
#pragma unroll
    for (int s = 0; s < 4; ++s) d[s] = v[s] - mean[s];
#pragma unroll
    for (int s = 0; s < 4; ++s) var[s] = wsum(d[s] * d[s]) * (1.0f / PDIM);
#pragma unroll
    for (int s = 0; s < 4; ++s) {
        float ln = d[s] * rsqrtf(var[s] + 1e-5f) * gd + bd;
        dot[s] = wsum(ln * pbs);
    }
    if (lane == 0) {
        mask[l * LSEQ + m0]     = (dot[0] + dot[2]) * (1.0f / (BATCH * NHEAD));
        mask[l * LSEQ + m0 + 1] = (dot[1] + dot[3]) * (1.0f / (BATCH * NHEAD));
    }
}

// seq layernorm: one row per block
__global__ void k_ln_seq(const float* __restrict__ h, const float* __restrict__ g,
                         const float* __restrict__ b, float* __restrict__ out) {
    __shared__ float red[8];
    int row = blockIdx.x;
    int t = threadIdx.x;
    int w = t >> 6, lane = t & 63;
    float v = h[row * HD + t];
    float s = wsum(v);
    if (lane == 0) red[w] = s;
    __syncthreads();
    float mean = (red[0] + red[1] + red[2] + red[3]) * (1.0f / HD);
    float d = v - mean;
    float q = wsum(d * d);
    if (lane == 0) red[4 + w] = q;
    __syncthreads();
    float var = (red[4] + red[5] + red[6] + red[7]) * (1.0f / HD);
    out[row * HD + t] = d * rsqrtf(var + 1e-5f) * g[t] + b[t];
}

// qkv = seq_n @ in_w + in_b ; 8 rows per block
__global__ void k_qkv(const float* __restrict__ sn, const float* __restrict__ w,
                      const float* __restrict__ bias, float* __restrict__ qkv) {
    __shared__ float xs[8][HD];
    int r0 = blockIdx.x * 8;
    int t = threadIdx.x;
#pragma unroll
    for (int r = 0; r < 8; ++r) xs[r][t] = sn[(r0 + r) * HD + t];
    __syncthreads();
#pragma unroll
    for (int c = 0; c < 3; ++c) {
        int j = c * HD + t;
        float acc[8];
#pragma unroll
        for (int r = 0; r < 8; ++r) acc[r] = 0.0f;
        for (int a = 0; a < HD; ++a) {
            float wv = w[a * 768 + j];
#pragma unroll
            for (int r = 0; r < 8; ++r) acc[r] += xs[r][a] * wv;
        }
        float bv = bias[j];
#pragma unroll
        for (int r = 0; r < 8; ++r) qkv[(r0 + r) * 768 + j] = acc[r] + bv;
    }
}

// attention for one (b, nh, l) per block
__global__ void k_attn(const float* __restrict__ qkv, const float* __restrict__ mask,
                       float* __restrict__ o) {
    __shared__ __align__(16) float qs[64];
    __shared__ float sc[LSEQ];
    __shared__ float red[8];
    __shared__ float op[4][64];
    int bid = blockIdx.x;
    int l = bid % LSEQ;
    int nh = (bid / LSEQ) & 3;
    int b = bid / (LSEQ * NHEAD);
    int t = threadIdx.x;
    int w = t >> 6, lane = t & 63;
    const float* qbase = qkv + ((size_t)(b * LSEQ + l)) * 768 + nh * 64;
    if (t < 64) qs[t] = qbase[t];
    __syncthreads();
    float lmax = -1e30f;
    float myv[2];
#pragma unroll
    for (int it = 0; it < 2; ++it) {
        int m = t + it * 256;
        if (m < LSEQ) {
            const float* kb = qkv + ((size_t)(b * LSEQ + m)) * 768 + 256 + nh * 64;
            const float4* k4 = (const float4*)kb;
            const float4* q4 = (const float4*)qs;
            float acc = 0.0f;
#pragma unroll
            for (int a = 0; a < 16; ++a) {
                float4 kv = k4[a], qv = q4[a];
                acc += qv.x * kv.x + qv.y * kv.y + qv.z * kv.z + qv.w * kv.w;
            }
            float s = acc * 0.125f + mask[l * LSEQ + m];
            myv[it] = s;
            lmax = fmaxf(lmax, s);
        } else myv[it] = -1e30f;
    }
    float wm = wmax(lmax);
    if (lane == 0) red[w] = wm;
    __syncthreads();
    float gmax = fmaxf(fmaxf(red[0], red[1]), fmaxf(red[2], red[3]));
    float lsum = 0.0f;
#pragma unroll
    for (int it = 0; it < 2; ++it) {
        int m = t + it * 256;
        if (m < LSEQ) {
            float e = expf(myv[it] - gmax);
            sc[m] = e;
            lsum += e;
        }
    }
    float ws = wsum(lsum);
    if (lane == 0) red[4 + w] = ws;
    __syncthreads();
    float inv = 1.0f / (red[4] + red[5] + red[6] + red[7]);
    int d = t & 63, gq = t >> 6;
    float part = 0.0f;
    for (int m = gq * 96; m < (gq + 1) * 96; ++m)
        part += sc[m] * qkv[((size_t)(b * LSEQ + m)) * 768 + 512 + nh * 64 + d];
    op[gq][d] = part;
    __syncthreads();
    if (t < 64) {
        float ov = (op[0][t] + op[1][t] + op[2][t] + op[3][t]) * inv;
        o[((size_t)(b * LSEQ + l)) * HD + nh * 64 + t] = ov;
    }
}

// h += o @ out_w + out_b ; 8 rows per block
__global__ void k_outproj(const float* __restrict__ o, const float* __restrict__ w,
                          const float* __restrict__ bias, float* __restrict__ h) {
    __shared__ float os[8][HD];
    int r0 = blockIdx.x * 8;
    int t = threadIdx.x;
#pragma unroll
    for (int r = 0; r < 8; ++r) os[r][t] = o[(r0 + r) * HD + t];
    __syncthreads();
    float acc[8] = {};
    for (int a = 0; a < HD; ++a) {
        float wv = w[a * HD + t];
#pragma unroll
        for (int r = 0; r < 8; ++r) acc[r] += os[r][a] * wv;
    }
    float bv = bias[t];
#pragma unroll
    for (int r = 0; r < 8; ++r) h[(r0 + r) * HD + t] += acc[r] + bv;
}

// mid = gelu(LN(h) @ ff_w1 + b1) ; 8 rows per block
__global__ void k_ff1(const float* __restrict__ h, const float* __restrict__ g,
                      const float* __restrict__ bb, const float* __restrict__ w,
                      const float* __restrict__ b1, float* __restrict__ mid) {
    __shared__ float hs[8][HD];
    __shared__ float red[8];
    int r0 = blockIdx.x * 8;
    int t = threadIdx.x;
    int wv_ = t >> 6, lane = t & 63;
#pragma unroll
    for (int r = 0; r < 8; ++r) hs[r][t] = h[(r0 + r) * HD + t];
    __syncthreads();
    float gt = g[t], bt = bb[t];
    for (int r = 0; r < 8; ++r) {
        float v = hs[r][t];
        float s = wsum(v);
        if (lane == 0) red[wv_] = s;
        __syncthreads();
        float mean = (red[0] + red[1] + red[2] + red[3]) * (1.0f / HD);
        float d = v - mean;
        float q = wsum(d * d);
        if (lane == 0) red[4 + wv_] = q;
        __syncthreads();
        float var = (red[4] + red[5] + red[6] + red[7]) * (1.0f / HD);
        hs[r][t] = d * rsqrtf(var + 1e-5f) * gt + bt;
        __syncthreads();
    }
#pragma unroll
    for (int c = 0; c < 4; ++c) {
        int j = c * HD + t;
        float acc[8] = {};
        for (int a = 0; a < HD; ++a) {
            float wv = w[a * 1024 + j];
#pragma unroll
            for (int r = 0; r < 8; ++r) acc[r] += hs[r][a] * wv;
        }
        float bv = b1[j];
#pragma unroll
        for (int r = 0; r < 8; ++r) mid[(r0 + r) * 1024 + j] = gelu_erf(acc[r] + bv);
    }
}

// h += mid @ ff_w2 + b2 ; 8 rows per block
__global__ void k_ff2(const float* __restrict__ mid, const float* __restrict__ w,
                      const float* __restrict__ b2, float* __restrict__ h) {
    __shared__ float ms[8 * 1024];
    int r0 = blockIdx.x * 8;
    int t = threadIdx.x;
    for (int n = t; n < 8192; n += 256) ms[n] = mid[r0 * 1024 + n];
    __syncthreads();
    float acc[8] = {};
    for (int a = 0; a < 1024; ++a) {
        float wv = w[a * HD + t];
#pragma unroll
        for (int r = 0; r < 8; ++r) acc[r] += ms[r * 1024 + a] * wv;
    }
    float bv = b2[t];
#pragma unroll
    for (int r = 0; r < 8; ++r) h[(r0 + r) * HD + t] += acc[r] + bv;
}

// ============ MFMA pair-update ============
// pair[b,l,j,:] += gelu(LN(oi+oj) @ W1' + b1') @ W2 + b2, computed TRANSPOSED:
// D1 = W1'^T · z^T  (rows=mid c, cols=pixel), D2 = W2^T · u (rows=out e, cols=pixel).
// Wave handles 32 pixels, no LDS, no __syncthreads. 3-product split-bf16 per GEMM.
// C-layout (32x32): col=lane&31 (pixel), row=(reg&3)+8*(reg>>2)+4*(lane>>5).
// A/B frag: m(or n)=lane&31, k=(lane>>5)*8+j.
__global__ void __launch_bounds__(256) k_pair_upd(
    const float* __restrict__ ojc,   // centered oj         (B,L,64)
    const float* __restrict__ oic,   // centered oi+outer_b (B,L,64)
    const unsigned short* __restrict__ w1hT, const unsigned short* __restrict__ w1lT,
    const float* __restrict__ b1p,
    const unsigned short* __restrict__ w2hT, const unsigned short* __restrict__ w2lT,
    const float* __restrict__ b2, float* __restrict__ pair) {
    int blk = blockIdx.x;            // row*3 + seg
    int row = blk / 3, seg = blk % 3;
    int b = row / LSEQ;
    int t = threadIdx.x;
    int wave = t >> 6, lane = t & 63;
    int pl = lane & 31, hq = lane >> 5;
    int p = seg * 128 + wave * 32 + pl;          // j index within pair row
    const float* ojr = ojc + ((size_t)b * LSEQ + p) * 64;
    const float* oir = oic + (size_t)row * 64;
    float* prp = pair + ((size_t)row * LSEQ + p) * 64;

    // phase A: v = oi+oj (pre-centered => mean 0), rsqrt scale, bf16 split frags
    float v[32];
#pragma unroll
    for (int s = 0; s < 4; ++s) {
        int k0 = 16 * s + 8 * hq;
#pragma unroll
        for (int j = 0; j < 8; ++j) v[8 * s + j] = ojr[k0 + j] + oir[k0 + j];
    }
    float ss = 0.0f;
#pragma unroll
    for (int i = 0; i < 32; ++i) ss = fmaf(v[i], v[i], ss);
    ss += __shfl_xor(ss, 32);
    float rs = rsqrtf(ss * (1.0f / PDIM) + 1e-5f);
    bf16x8 zh[4], zl[4];
#pragma unroll
    for (int s = 0; s < 4; ++s)
#pragma unroll
        for (int j = 0; j < 8; ++j) {
            unsigned short h, l;
            split_bf(v[8 * s + j] * rs, h, l);
            zh[s][j] = (short)h; zl[s][j] = (short)l;
        }

    // GEMM1: D1[c][pixel], acc init = b1'
    f32x16 acc0, acc1;
#pragma unroll
    for (int r = 0; r < 16; ++r) {
        int rr = (r & 3) + 8 * (r >> 2) + 4 * hq;
        acc0[r] = b1p[rr];
        acc1[r] = b1p[32 + rr];
    }
#pragma unroll
    for (int s = 0; s < 4; ++s) {
        int ko = 16 * s + 8 * hq;
        bf16x8 a0h = *(const bf16x8*)(w1hT + (pl << 6) + ko);
        bf16x8 a0l = *(const bf16x8*)(w1lT + (pl << 6) + ko);
        bf16x8 a1h = *(const bf16x8*)(w1hT + ((32 + pl) << 6) + ko);
        bf16x8 a1l = *(const bf16x8*)(w1lT + ((32 + pl) << 6) + ko);
        acc0 = MFMA32(a0h, zh[s], acc0);
        acc0 = MFMA32(a0h, zl[s], acc0);
        acc0 = MFMA32(a0l, zh[s], acc0);
        acc1 = MFMA32(a1h, zh[s], acc1);
        acc1 = MFMA32(a1h, zl[s], acc1);
        acc1 = MFMA32(a1l, zh[s], acc1);
    }
    float u0[16], u1[16];
#pragma unroll
    for (int r = 0; r < 16; ++r) { u0[r] = gelu_erf(acc0[r]); u1[r] = gelu_erf(acc1[r]); }

    // exchange with partner lane (hq^1): each side sends the c-rows the partner
    // needs for its B2 K-range. hq0 sends regs{4-7,12-15}, hq1 sends regs{0-3,8-11}.
    float rA0[4], rB0[4], rA1[4], rB1[4];
#pragma unroll
    for (int i = 0; i < 4; ++i) {
        rA0[i] = __shfl_xor(hq ? u0[i] : u0[4 + i], 32);
        rB0[i] = __shfl_xor(hq ? u0[8 + i] : u0[12 + i], 32);
        rA1[i] = __shfl_xor(hq ? u1[i] : u1[4 + i], 32);
        rB1[i] = __shfl_xor(hq ? u1[8 + i] : u1[12 + i], 32);
    }
    // build B2 frags: k = 16s+8hq+j  (s = 2*tt + q)
    bf16x8 uh[4], ul[4];
#pragma unroll
    for (int s = 0; s < 4; ++s) {
        int tt = s >> 1, q = s & 1;
#pragma unroll
        for (int i = 0; i < 4; ++i) {
            float own_f = q ? (tt ? u1[8 + i] : u0[8 + i]) : (tt ? u1[i] : u0[i]);
            float own_s = q ? (tt ? u1[12 + i] : u0[12 + i]) : (tt ? u1[4 + i] : u0[4 + i]);
            float rcv   = q ? (tt ? rB1[i] : rB0[i]) : (tt ? rA1[i] : rA0[i]);
            float f  = hq ? rcv : own_f;
            float g2 = hq ? own_s : rcv;
            unsigned short h, l;
            split_bf(f, h, l);  uh[s][i] = (short)h;     ul[s][i] = (short)l;
            split_bf(g2, h, l); uh[s][4 + i] = (short)h; ul[s][4 + i] = (short)l;
        }
    }

    // GEMM2: D2[e][pixel], acc init = b2[e] + pair_old[pixel][e]
    f32x16 c0, c1;
#pragma unroll
    for (int r = 0; r < 16; ++r) {
        int rr = (r & 3) + 8 * (r >> 2) + 4 * hq;
        c0[r] = b2[rr] + prp[rr];
        c1[r] = b2[32 + rr] + prp[32 + rr];
    }
#pragma unroll
    for (int s = 0; s < 4; ++s) {
        int ko = 16 * s + 8 * hq;
        bf16x8 a0h = *(const bf16x8*)(w2hT + (pl << 6) + ko);
        bf16x8 a0l = *(const bf16x8*)(w2lT + (pl << 6) + ko);
        bf16x8 a1h = *(const bf16x8*)(w2hT + ((32 + pl) << 6) + ko);
        bf16x8 a1l = *(const bf16x8*)(w2lT + ((32 + pl) << 6) + ko);
        c0 = MFMA32(a0h, uh[s], c0);
        c0 = MFMA32(a0h, ul[s], c0);
        c0 = MFMA32(a0l, uh[s], c0);
        c1 = MFMA32(a1h, uh[s], c1);
        c1 = MFMA32(a1h, ul[s], c1);
        c1 = MFMA32(a1l, uh[s], c1);
    }
#pragma unroll
    for (int r = 0; r < 16; ++r) {
        int rr = (r & 3) + 8 * (r >> 2) + 4 * hq;
        prp[rr] = c0[r];
        prp[32 + rr] = c1[r];
    }
}

// ============ MFMA distogram head ============
// logits = gelu(LN(pair)@dhW1'+b1')@dh_w2 + dh_b2 ; same transposed scheme;
// bin 64 handled as a VALU dot over u.
__global__ void __launch_bounds__(256) k_dist(
    const float* __restrict__ pair,
    const unsigned short* __restrict__ w1hT, const unsigned short* __restrict__ w1lT,
    const float* __restrict__ b1p,
    const unsigned short* __restrict__ w2hT, const unsigned short* __restrict__ w2lT,
    const float* __restrict__ w2c, const float* __restrict__ b2,
    float* __restrict__ out) {
    int blk = blockIdx.x;
    int row = blk / 3, seg = blk % 3;
    int t = threadIdx.x;
    int wave = t >> 6, lane = t & 63;
    int pl = lane & 31, hq = lane >> 5;
    int p = seg * 128 + wave * 32 + pl;
    const float* prp = pair + ((size_t)row * LSEQ + p) * 64;
    float v[32];
#pragma unroll
    for (int s = 0; s < 4; ++s) {
        int k0 = 16 * s + 8 * hq;
#pragma unroll
        for (int j = 0; j < 8; ++j) v[8 * s + j] = prp[k0 + j];
    }
    float sm = 0.0f;
#pragma unroll
    for (int i = 0; i < 32; ++i) sm += v[i];
    sm += __shfl_xor(sm, 32);
    float mean = sm * (1.0f / PDIM);
    float ss = 0.0f;
#pragma unroll
    for (int i = 0; i < 32; ++i) { v[i] -= mean; ss = fmaf(v[i], v[i], ss); }
    ss += __shfl_xor(ss, 32);
    float rs = rsqrtf(ss * (1.0f / PDIM) + 1e-5f);
    bf16x8 zh[4], zl[4];
#pragma unroll
    for (int s = 0; s < 4; ++s)
#pragma unroll
        for (int j = 0; j < 8; ++j) {
            unsigned short h, l;
            split_bf(v[8 * s + j] * rs, h, l);
            zh[s][j] = (short)h; zl[s][j] = (short)l;
        }
    f32x16 acc0, acc1;
#pragma unroll
    for (int r = 0; r < 16; ++r) {
        int rr = (r & 3) + 8 * (r >> 2) + 4 * hq;
        acc0[r] = b1p[rr];
        acc1[r] = b1p[32 + rr];
    }
#pragma unroll
    for (int s = 0; s < 4; ++s) {
        int ko = 16 * s + 8 * hq;
        bf16x8 a0h = *(const bf16x8*)(w1hT + (pl << 6) + ko);
        bf16x8 a0l = *(const bf16x8*)(w1lT + (pl << 6) + ko);
        bf16x8 a1h = *(const bf16x8*)(w1hT + ((32 + pl) << 6) + ko);
        bf16x8 a1l = *(const bf16x8*)(w1lT + ((32 + pl) << 6) + ko);
        acc0 = MFMA32(a0h, zh[s], acc0);
        acc0 = MFMA32(a0h, zl[s], acc0);
        acc0 = MFMA32(a0l, zh[s], acc0);
        acc1 = MFMA32(a1h, zh[s], acc1);
        acc1 = MFMA32(a1h, zl[s], acc1);
        acc1 = MFMA32(a1l, zh[s], acc1);
    }
    float u0[16], u1[16];
    float p64 = 0.0f;
#pragma unroll
    for (int r = 0; r < 16; ++r) {
        int rr = (r & 3) + 8 * (r >> 2) + 4 * hq;
        u0[r] = gelu_erf(acc0[r]);
        u1[r] = gelu_erf(acc1[r]);
        p64 = fmaf(u0[r], w2c[rr], p64);
        p64 = fmaf(u1[r], w2c[32 + rr], p64);
    }
    p64 += __shfl_xor(p64, 32);
    float rA0[4], rB0[4], rA1[4], rB1[4];
#pragma unroll
    for (int i = 0; i < 4; ++i) {
        rA0[i] = __shfl_xor(hq ? u0[i] : u0[4 + i], 32);
        rB0[i] = __shfl_xor(hq ? u0[8 + i] : u0[12 + i], 32);
        rA1[i] = __shfl_xor(hq ? u1[i] : u1[4 + i], 32);
        rB1[i] = __shfl_xor(hq ? u1[8 + i] : u1[12 + i], 32);
    }
    bf16x8 uh[4], ul[4];
#pragma unroll
    for (int s = 0; s < 4; ++s) {
        int tt = s >> 1, q = s & 1;
#pragma unroll
        for (int i = 0; i < 4; ++i) {
            float own_f = q ? (tt ? u1[8 + i] : u0[8 + i]) : (tt ? u1[i] : u0[i]);
            float own_s = q ? (tt ? u1[12 + i] : u0[12 + i]) : (tt ? u1[4 + i] : u0[4 + i]);
            float rcv   = q ? (tt ? rB1[i] : rB0[i]) : (tt ? rA1[i] : rA0[i]);
            float f  = hq ? rcv : own_f;
            float g2 = hq ? own_s : rcv;
            unsigned short h, l;
            split_bf(f, h, l);  uh[s][i] = (short)h;     ul[s][i] = (short)l;
            split_bf(g2, h, l); uh[s][4 + i] = (short)h; ul[s][4 + i] = (short)l;
        }
    }
    f32x16 c0, c1;
#pragma unroll
    for (int r = 0; r < 16; ++r) {
        int rr = (r & 3) + 8 * (r >> 2) + 4 * hq;
        c0[r] = b2[rr];
        c1[r] = b2[32 + rr];
    }
#pragma unroll
    for (int s = 0; s < 4; ++s) {
        int ko = 16 * s + 8 * hq;
        bf16x8 a0h = *(const bf16x8*)(w2hT + (pl << 6) + ko);
        bf16x8 a0l = *(const bf16x8*)(w2lT + (pl << 6) + ko);
        bf16x8 a1h = *(const bf16x8*)(w2hT + ((32 + pl) << 6) + ko);
        bf16x8 a1l = *(const bf16x8*)(w2lT + ((32 + pl) << 6) + ko);
        c0 = MFMA32(a0h, uh[s], c0);
        c0 = MFMA32(a0h, ul[s], c0);
        c0 = MFMA32(a0l, uh[s], c0);
        c1 = MFMA32(a1h, uh[s], c1);
        c1 = MFMA32(a1h, ul[s], c1);
        c1 = MFMA32(a1l, uh[s], c1);
    }
    float* orow = out + ((size_t)row * LSEQ + p) * NBINS;
#pragma unroll
    for (int r = 0; r < 16; ++r) {
        int rr = (r & 3) + 8 * (r >> 2) + 4 * hq;
        orow[rr] = c0[r];
        orow[32 + rr] = c1[r];
    }
    if (hq == 0) orow[64] = p64 + b2[64];
}

// out = (out + out^T(1,2)) / 2, in place
__global__ void k_sym(float* __restrict__ out) {
    int row = blockIdx.x;            // b*L + l
    int b = row / LSEQ, l = row % LSEQ;
    int t = threadIdx.x;
    float* obp = out + (size_t)b * LSEQ * LSEQ * NBINS;
    int tot = (LSEQ - l) * NBINS;
    for (int n = t; n < tot; n += 256) {
        int m = l + n / NBINS;
        int k = n % NBINS;
        size_t i1 = ((size_t)l * LSEQ + m) * NBINS + k;
        size_t i2 = ((size_t)m * LSEQ + l) * NBINS + k;
        float a = obp[i1], c = obp[i2];
        float vv = 0.5f * (a + c);
        obp[i1] = vv;
        obp[i2] = vv;
    }
}

extern "C" void kernel_launch(void* const* d_in, const int* in_sizes, int n_in,
                              void* d_out, int out_size, void* d_ws, size_t ws_size,
                              hipStream_t stream) {
    const float* x        = (const float*)d_in[0];
    const float* rp_w     = (const float*)d_in[1];
    const float* rp_b     = (const float*)d_in[2];
    const float* pos      = (const float*)d_in[3];
    const float* pii_w    = (const float*)d_in[4];
    const float* pii_b    = (const float*)d_in[5];
    const float* pij_w    = (const float*)d_in[6];
    const float* pij_b    = (const float*)d_in[7];
    const float* rel_emb  = (const float*)d_in[8];
    const float* ln_seq_g = (const float*)d_in[9];
    const float* ln_seq_b = (const float*)d_in[10];
    const float* ln_pair_g= (const float*)d_in[11];
    const float* ln_pair_b= (const float*)d_in[12];
    const float* pb_w     = (const float*)d_in[13];
    const float* in_w     = (const float*)d_in[14];
    const float* in_b     = (const float*)d_in[15];
    const float* out_w    = (const float*)d_in[16];
    const float* out_b    = (const float*)d_in[17];
    const float* ff_ln_g  = (const float*)d_in[18];
    const float* ff_ln_b  = (const float*)d_in[19];
    const float* ff_w1    = (const float*)d_in[20];
    const float* ff_b1    = (const float*)d_in[21];
    const float* ff_w2    = (const float*)d_in[22];
    const float* ff_b2    = (const float*)d_in[23];
    const float* pu_ln_g  = (const float*)d_in[24];
    const float* pu_ln_b  = (const float*)d_in[25];
    const float* pu_w1    = (const float*)d_in[26];
    const float* pu_b1    = (const float*)d_in[27];
    const float* pu_w2    = (const float*)d_in[28];
    const float* pu_b2    = (const float*)d_in[29];
    const float* outer_w  = (const float*)d_in[30];
    const float* outer_b  = (const float*)d_in[31];
    const float* dh_ln_g  = (const float*)d_in[32];
    const float* dh_ln_b  = (const float*)d_in[33];
    const float* dh_w1    = (const float*)d_in[34];
    const float* dh_b1    = (const float*)d_in[35];
    const float* dh_w2    = (const float*)d_in[36];
    const float* dh_b2    = (const float*)d_in[37];
    float* outp = (float*)d_out;

    float* W = (float*)d_ws;
    float* h    = W;  W += BATCH * LSEQ * HD;
    float* sn   = W;  W += BATCH * LSEQ * HD;
    float* qkv  = W;  W += BATCH * LSEQ * 3 * HD;
    float* ob   = W;  W += BATCH * LSEQ * HD;
    float* mid  = W;  W += BATCH * LSEQ * 4 * HD;
    float* mask = W;  W += LSEQ * LSEQ;
    float* poi  = W;  W += BATCH * LSEQ * PDIM;
    float* poj  = W;  W += BATCH * LSEQ * PDIM;
    float* b1p  = W;  W += 5 * 64;
    float* w2c  = W;  W += 64;
    unsigned short* w1hT = (unsigned short*)W;  W += 5 * 2048;
    unsigned short* w1lT = (unsigned short*)W;  W += 5 * 2048;
    unsigned short* w2hT = (unsigned short*)W;  W += 5 * 2048;
    unsigned short* w2lT = (unsigned short*)W;  W += 5 * 2048;
    float* pair = W;  W += (size_t)BATCH * LSEQ * LSEQ * PDIM;

    const int rows = BATCH * LSEQ;   // 768

    k_prep<<<5, 64, 0, stream>>>(pu_ln_g, pu_ln_b, pu_w1, pu_b1, pu_w2,
                                 dh_ln_g, dh_ln_b, dh_w1, dh_b1, dh_w2,
                                 w1hT, w1lT, w2hT, w2lT, b1p, w2c);
    k_h_init<<<rows, 256, 0, stream>>>(x, rp_w, rp_b, pos, h);
    k_proj2<<<rows, 128, 0, stream>>>(h, pii_w, pij_w, pii_b, pij_b, 0, poi, poj);
    k_pair_init<<<rows, 256, 0, stream>>>(poi, poj, rel_emb, pair);

    for (int i = 0; i < 4; ++i) {
        k_ln_seq<<<rows, 256, 0, stream>>>(h, ln_seq_g + i * HD, ln_seq_b + i * HD, sn);
        k_mask<<<LSEQ * LSEQ / 8, 256, 0, stream>>>(pair, ln_pair_g + i * PDIM,
                                                    ln_pair_b + i * PDIM,
                                                    pb_w + i * PDIM * NHEAD, mask);
        k_qkv<<<rows / 8, 256, 0, stream>>>(sn, in_w + i * HD * 3 * HD, in_b + i * 3 * HD, qkv);
        k_attn<<<BATCH * NHEAD * LSEQ, 256, 0, stream>>>(qkv, mask, ob);
        k_outproj<<<rows / 8, 256, 0, stream>>>(ob, out_w + i * HD * HD, out_b + i * HD, h);
        k_ff1<<<rows / 8, 256, 0, stream>>>(h, ff_ln_g + i * HD, ff_ln_b + i * HD,
                                            ff_w1 + i * HD * 4 * HD, ff_b1 + i * 4 * HD, mid);
        k_ff2<<<rows / 8, 256, 0, stream>>>(mid, ff_w2 + i * 4 * HD * HD, ff_b2 + i * HD, h);
        // centered oi+outer_b (poi) and centered oj (poj)
        k_proj2<<<rows, 128, 0, stream>>>(h, outer_w + i * 2 * HD * PDIM,
                                          outer_w + i * 2 * HD * PDIM + HD * PDIM,
                                          outer_b + i * PDIM, nullptr, 1, poi, poj);
        k_pair_upd<<<rows * 3, 256, 0, stream>>>(poj, poi,
                                                 w1hT + i * 4096, w1lT + i * 4096,
                                                 b1p + i * 64,
                                                 w2hT + i * 4096, w2lT + i * 4096,
                                                 pu_b2 + i * PDIM, pair);
    }

    k_dist<<<rows * 3, 256, 0, stream>>>(pair, w1hT + 4 * 4096, w1lT + 4 * 4096,
                                         b1p + 4 * 64, w2hT + 4 * 4096, w2lT + 4 * 4096,
                                         w2c, dh_b2, outp);
    k_sym<<<rows, 256, 0, stream>>>(outp);
}

// Round 5
// 1288.908 us; speedup vs baseline: 4.1693x; 1.5622x over previous
//
#include <hip/hip_runtime.h>
#include <math.h>

#define LSEQ 384
#define HD 256
#define PDIM 64
#define NHEAD 4
#define NBINS 65
#define BATCH 2

typedef __attribute__((ext_vector_type(8))) short bf16x8;
typedef __attribute__((ext_vector_type(16))) float f32x16;
#define MFMA32(a, b, c) __builtin_amdgcn_mfma_f32_32x32x16_bf16(a, b, c, 0, 0, 0)

// ---- DPP-based wave64 reductions (VALU pipe, not LDS) ----
template<int CTRL, int RMASK>
__device__ __forceinline__ float dpp_sum_step(float v) {
    int x = __builtin_amdgcn_update_dpp(0, __float_as_int(v), CTRL, RMASK, 0xf, true);
    return v + __int_as_float(x);
}
template<int CTRL, int RMASK>
__device__ __forceinline__ float dpp_max_step(float v) {
    int x = __builtin_amdgcn_update_dpp(__float_as_int(v), __float_as_int(v), CTRL, RMASK, 0xf, false);
    return fmaxf(v, __int_as_float(x));
}
__device__ __forceinline__ float wsum(float v) {
    v = dpp_sum_step<0x111, 0xf>(v);
    v = dpp_sum_step<0x112, 0xf>(v);
    v = dpp_sum_step<0x114, 0xf>(v);
    v = dpp_sum_step<0x118, 0xf>(v);
    v = dpp_sum_step<0x142, 0xa>(v);
    v = dpp_sum_step<0x143, 0xc>(v);
    return __int_as_float(__builtin_amdgcn_readlane(__float_as_int(v), 63));
}
__device__ __forceinline__ float wmax(float v) {
    v = dpp_max_step<0x111, 0xf>(v);
    v = dpp_max_step<0x112, 0xf>(v);
    v = dpp_max_step<0x114, 0xf>(v);
    v = dpp_max_step<0x118, 0xf>(v);
    v = dpp_max_step<0x142, 0xa>(v);
    v = dpp_max_step<0x143, 0xc>(v);
    return __int_as_float(__builtin_amdgcn_readlane(__float_as_int(v), 63));
}
__device__ __forceinline__ float gelu_erf(float x) {
    return 0.5f * x * (1.0f + erff(x * 0.70710678f));
}

// bf16 RNE conversion + error-compensated split: x ~= hi + lo
__device__ __forceinline__ unsigned short f2bf(float x) {
    unsigned u = __float_as_uint(x);
    unsigned r = (u + 0x7fff + ((u >> 16) & 1)) >> 16;
    return (unsigned short)r;
}
__device__ __forceinline__ float bf2f(unsigned short h) {
    return __uint_as_float(((unsigned)h) << 16);
}
__device__ __forceinline__ void split_bf(float x, unsigned short& h, unsigned short& l) {
    h = f2bf(x);
    l = f2bf(x - bf2f(h));
}

// h[b,l,:] = x[b,l,:] @ rp_w + rp_b + pos[l,:]
__global__ void k_h_init(const float* __restrict__ x, const float* __restrict__ rp_w,
                         const float* __restrict__ rp_b, const float* __restrict__ pos,
                         float* __restrict__ h) {
    __shared__ float xs[48];
    int row = blockIdx.x;            // b*L + l
    int l = row % LSEQ;
    int t = threadIdx.x;
    if (t < 48) xs[t] = x[row * 48 + t];
    __syncthreads();
    float acc = rp_b[t] + pos[l * HD + t];
#pragma unroll 8
    for (int a = 0; a < 48; ++a) acc += xs[a] * rp_w[a * HD + t];
    h[row * HD + t] = acc;
}

// pA[row,:] = h[row,:] @ wA (+ bA);  pB[row,:] = h[row,:] @ wB (+ bB)
// center!=0: subtract per-row mean (LN-mean elimination downstream)
__global__ void k_proj2(const float* __restrict__ h, const float* __restrict__ wA,
                        const float* __restrict__ wB, const float* __restrict__ bA,
                        const float* __restrict__ bB, int center,
                        float* __restrict__ pA, float* __restrict__ pB) {
    __shared__ float hs[HD];
    int row = blockIdx.x;
    int t = threadIdx.x;
    hs[t] = h[row * HD + t];
    hs[t + 128] = h[row * HD + t + 128];
    __syncthreads();
    int col = t & 63;
    const float* w = (t < 64) ? wA : wB;
    const float* bias = (t < 64) ? bA : bB;
    float acc = bias ? bias[col] : 0.0f;
#pragma unroll 8
    for (int a = 0; a < HD; ++a) acc += hs[a] * w[a * PDIM + col];
    if (center) {
        float mean = wsum(acc) * (1.0f / PDIM);
        acc -= mean;
    }
    float* p = (t < 64) ? pA : pB;
    p[row * PDIM + col] = acc;
}

// pair[b,i,j,:] = pi[b,i,:] + pj[b,j,:] + rel_emb[clip(j-i)+32,:]
__global__ void k_pair_init(const float* __restrict__ pi, const float* __restrict__ pj,
                            const float* __restrict__ rel_emb, float* __restrict__ pair) {
    __shared__ float pis[PDIM];
    int row = blockIdx.x;            // b*L + i
    int b = row / LSEQ, i = row % LSEQ;
    int t = threadIdx.x;
    if (t < PDIM) pis[t] = pi[row * PDIM + t];
    __syncthreads();
    const float* pjb = pj + (size_t)b * LSEQ * PDIM;
    float* pr = pair + (size_t)row * LSEQ * PDIM;
    for (int n = t; n < LSEQ * PDIM; n += 256) {
        int j = n >> 6, d = n & 63;
        int r = j - i; r = r < -32 ? -32 : (r > 32 ? 32 : r); r += 32;
        pr[n] = pis[d] + pjb[j * PDIM + d] + rel_emb[r * PDIM + d];
    }
}

// prep: fold LN g/b into W1 (b1p = b1 + bb@W1), split all pair-MLP weights into
// bf16 hi/lo, stored TRANSPOSED [out][k] for direct 16B MFMA A-frag loads.
__global__ void k_prep(const float* __restrict__ pu_ln_g, const float* __restrict__ pu_ln_b,
                       const float* __restrict__ pu_w1, const float* __restrict__ pu_b1,
                       const float* __restrict__ pu_w2,
                       const float* __restrict__ dh_ln_g, const float* __restrict__ dh_ln_b,
                       const float* __restrict__ dh_w1, const float* __restrict__ dh_b1,
                       const float* __restrict__ dh_w2,
                       unsigned short* __restrict__ w1hT, unsigned short* __restrict__ w1lT,
                       unsigned short* __restrict__ w2hT, unsigned short* __restrict__ w2lT,
                       float* __restrict__ b1p, float* __restrict__ w2c) {
    int i = blockIdx.x;              // 0..4
    int c = threadIdx.x;             // 0..63 = output row of transposed arrays
    const float *g, *bb, *w1, *b1, *w2;
    int w2s;
    if (i < 4) { g = pu_ln_g + i * 64; bb = pu_ln_b + i * 64; w1 = pu_w1 + i * 4096;
                 b1 = pu_b1 + i * 64; w2 = pu_w2 + i * 4096; w2s = 64; }
    else       { g = dh_ln_g; bb = dh_ln_b; w1 = dh_w1; b1 = dh_b1; w2 = dh_w2; w2s = 65; }
    float accb = b1[c];
    for (int k = 0; k < 64; ++k) {
        float wv = w1[k * 64 + c];
        accb += bb[k] * wv;
        unsigned short h, l;
        split_bf(g[k] * wv, h, l);                 // W1'[k][c] stored at [c][k]
        w1hT[i * 4096 + c * 64 + k] = h;
        w1lT[i * 4096 + c * 64 + k] = l;
        split_bf(w2[k * w2s + c], h, l);           // W2[k][c] stored at [c][k]
        w2hT[i * 4096 + c * 64 + k] = h;
        w2lT[i * 4096 + c * 64 + k] = l;
    }
    b1p[i * 64 + c] = accb;
    if (i == 4) w2c[c] = dh_w2[c * 65 + 64];
}

// prep: split+transpose seq weights to bf16 hi/lo [n][k] via 64x64 LDS tiles.
// src: [K][N] row-major, per-layer stride sstride; dst: [N][K], stride dstride.
__global__ void k_split_T(const float* __restrict__ src, unsigned short* __restrict__ dh,
                          unsigned short* __restrict__ dl, int K, int N,
                          int tiles_k, int tiles_n, size_t sstride, size_t dstride) {
    __shared__ float lds[64][65];
    int bid = blockIdx.x;
    int tpl = tiles_k * tiles_n;
    int layer = bid / tpl;
    int rest = bid % tpl;
    int kt = rest / tiles_n, nt = rest % tiles_n;
    const float* s = src + layer * sstride;
    int t = threadIdx.x, c = t & 63, r0 = t >> 6;
    for (int r = r0; r < 64; r += 4)
        lds[r][c] = s[(size_t)(kt * 64 + r) * N + nt * 64 + c];
    __syncthreads();
    unsigned short* oh = dh + layer * dstride;
    unsigned short* ol = dl + layer * dstride;
    for (int r = r0; r < 64; r += 4) {
        float v = lds[c][r];                       // src[kt*64+c][nt*64+r]
        unsigned short h, l;
        split_bf(v, h, l);
        size_t o = (size_t)(nt * 64 + r) * K + kt * 64 + c;
        oh[o] = h;
        ol[o] = l;
    }
}

// ============ generic MFMA seq GEMM ============
// OUT[m][n] = epi( X[m][:]@W + bias[n] + (R?R[m][n]:0) ), M=768 rows.
// W pre-split bf16 hi/lo transposed [n][k]. Wave = 32x32 tile, block = 4 waves.
template<bool GELU>
__global__ void __launch_bounds__(256) k_gemm(
    const float* __restrict__ X, const unsigned short* __restrict__ wTh,
    const unsigned short* __restrict__ wTl, const float* __restrict__ bias,
    const float* __restrict__ R, float* __restrict__ OUT, int K, int N) {
    int idx = blockIdx.x * 4 + (threadIdx.x >> 6);
    int lane = threadIdx.x & 63;
    int pl = lane & 31, hq = lane >> 5;
    int ntiles = N >> 5;
    int mt = idx / ntiles, nt = idx % ntiles;
    const float* xr = X + (size_t)(mt * 32 + pl) * K + 8 * hq;
    const unsigned short* bh = wTh + (size_t)(nt * 32 + pl) * K + 8 * hq;
    const unsigned short* bl = wTl + (size_t)(nt * 32 + pl) * K + 8 * hq;
    int n = nt * 32 + pl;
    float bv = bias[n];
    f32x16 acc;
#pragma unroll
    for (int r = 0; r < 16; ++r) {
        int mr = mt * 32 + (r & 3) + 8 * (r >> 2) + 4 * hq;
        acc[r] = bv + (R ? R[(size_t)mr * N + n] : 0.0f);
    }
#pragma unroll 4
    for (int s = 0; s < K; s += 16) {
        bf16x8 ah, al;
#pragma unroll
        for (int j = 0; j < 8; ++j) {
            unsigned short h, l;
            split_bf(xr[s + j], h, l);
            ah[j] = (short)h; al[j] = (short)l;
        }
        bf16x8 bhv = *(const bf16x8*)(bh + s);
        bf16x8 blv = *(const bf16x8*)(bl + s);
        acc = MFMA32(ah, bhv, acc);
        acc = MFMA32(al, bhv, acc);
        acc = MFMA32(ah, blv, acc);
    }
#pragma unroll
    for (int r = 0; r < 16; ++r) {
        int mr = mt * 32 + (r & 3) + 8 * (r >> 2) + 4 * hq;
        float v = acc[r];
        OUT[(size_t)mr * N + n] = GELU ? gelu_erf(v) : v;
    }
}

// mask[l,m] = (1/(B*NH)) * sum_b LN(pair[b,l,m,:]) . pbsum
__global__ void k_mask(const float* __restrict__ pair, const float* __restrict__ g,
                       const float* __restrict__ bb, const float* __restrict__ pbw,
                       float* __restrict__ mask) {
    int wid = (blockIdx.x * 4 + (threadIdx.x >> 6)) * 2;
    int lane = threadIdx.x & 63;
    int l = wid / LSEQ, m0 = wid % LSEQ;
    float gd = g[lane], bd = bb[lane];
    float pbs = pbw[lane * 4] + pbw[lane * 4 + 1] + pbw[lane * 4 + 2] + pbw[lane * 4 + 3];
    float v[4];
#pragma unroll
    for (int s = 0; s < 4; ++s) {
        int b = s >> 1, m = m0 + (s & 1);
        v[s] = pair[(((size_t)(b * LSEQ + l)) * LSEQ + m) * PDIM + lane];
    }
    float mean[4], d[4], var[4], dot[4];
#pragma unroll
    for (int s = 0; s < 4; ++s) mean[s] = wsum(v[s]) * (1.0f / PDIM);
#pragma unroll
    for (int s = 0; s < 4; ++s) d[s] = v[s] - mean[s];
#pragma unroll
    for (int s = 0; s < 4; ++s) var[s] = wsum(d[s] * d[s]) * (1.0f / PDIM);
#pragma unroll
    for (int s = 0; s < 4; ++s) {
        float ln = d[s] * rsqrtf(var[s] + 1e-5f) * gd + bd;
        dot[s] = wsum(ln * pbs);
    }
    if (lane == 0) {
        mask[l * LSEQ + m0]     = (dot[0] + dot[2]) * (1.0f / (BATCH * NHEAD));
        mask[l * LSEQ + m0 + 1] = (dot[1] + dot[3]) * (1.0f / (BATCH * NHEAD));
    }
}

// seq layernorm: one row per block
__global__ void k_ln_seq(const float* __restrict__ h, const float* __restrict__ g,
                         const float* __restrict__ b, float* __restrict__ out) {
    __shared__ float red[8];
    int row = blockIdx.x;
    int t = threadIdx.x;
    int w = t >> 6, lane = t & 63;
    float v = h[row * HD + t];
    float s = wsum(v);
    if (lane == 0) red[w] = s;
    __syncthreads();
    float mean = (red[0] + red[1] + red[2] + red[3]) * (1.0f / HD);
    float d = v - mean;
    float q = wsum(d * d);
    if (lane == 0) red[4 + w] = q;
    __syncthreads();
    float var = (red[4] + red[5] + red[6] + red[7]) * (1.0f / HD);
    out[row * HD + t] = d * rsqrtf(var + 1e-5f) * g[t] + b[t];
}

// attention for one (b, nh, l) per block
__global__ void k_attn(const float* __restrict__ qkv, const float* __restrict__ mask,
                       float* __restrict__ o) {
    __shared__ __align__(16) float qs[64];
    __shared__ float sc[LSEQ];
    __shared__ float red[8];
    __shared__ float op[4][64];
    int bid = blockIdx.x;
    int l = bid % LSEQ;
    int nh = (bid / LSEQ) & 3;
    int b = bid / (LSEQ * NHEAD);
    int t = threadIdx.x;
    int w = t >> 6, lane = t & 63;
    const float* qbase = qkv + ((size_t)(b * LSEQ + l)) * 768 + nh * 64;
    if (t < 64) qs[t] = qbase[t];
    __syncthreads();
    float lmax = -1e30f;
    float myv[2];
#pragma unroll
    for (int it = 0; it < 2; ++it) {
        int m = t + it * 256;
        if (m < LSEQ) {
            const float* kb = qkv + ((size_t)(b * LSEQ + m)) * 768 + 256 + nh * 64;
            const float4* k4 = (const float4*)kb;
            const float4* q4 = (const float4*)qs;
            float acc = 0.0f;
#pragma unroll
            for (int a = 0; a < 16; ++a) {
                float4 kv = k4[a], qv = q4[a];
                acc += qv.x * kv.x + qv.y * kv.y + qv.z * kv.z + qv.w * kv.w;
            }
            float s = acc * 0.125f + mask[l * LSEQ + m];
            myv[it] = s;
            lmax = fmaxf(lmax, s);
        } else myv[it] = -1e30f;
    }
    float wm = wmax(lmax);
    if (lane == 0) red[w] = wm;
    __syncthreads();
    float gmax = fmaxf(fmaxf(red[0], red[1]), fmaxf(red[2], red[3]));
    float lsum = 0.0f;
#pragma unroll
    for (int it = 0; it < 2; ++it) {
        int m = t + it * 256;
        if (m < LSEQ) {
            float e = expf(myv[it] - gmax);
            sc[m] = e;
            lsum += e;
        }
    }
    float ws = wsum(lsum);
    if (lane == 0) red[4 + w] = ws;
    __syncthreads();
    float inv = 1.0f / (red[4] + red[5] + red[6] + red[7]);
    int d = t & 63, gq = t >> 6;
    float part = 0.0f;
    for (int m = gq * 96; m < (gq + 1) * 96; ++m)
        part += sc[m] * qkv[((size_t)(b * LSEQ + m)) * 768 + 512 + nh * 64 + d];
    op[gq][d] = part;
    __syncthreads();
    if (t < 64) {
        float ov = (op[0][t] + op[1][t] + op[2][t] + op[3][t]) * inv;
        o[((size_t)(b * LSEQ + l)) * HD + nh * 64 + t] = ov;
    }
}

// ============ MFMA pair-update ============
__global__ void __launch_bounds__(256) k_pair_upd(
    const float* __restrict__ ojc,   // centered oj         (B,L,64)
    const float* __restrict__ oic,   // centered oi+outer_b (B,L,64)
    const unsigned short* __restrict__ w1hT, const unsigned short* __restrict__ w1lT,
    const float* __restrict__ b1p,
    const unsigned short* __restrict__ w2hT, const unsigned short* __restrict__ w2lT,
    const float* __restrict__ b2, float* __restrict__ pair) {
    int blk = blockIdx.x;            // row*3 + seg
    int row = blk / 3, seg = blk % 3;
    int b = row / LSEQ;
    int t = threadIdx.x;
    int wave = t >> 6, lane = t & 63;
    int pl = lane & 31, hq = lane >> 5;
    int p = seg * 128 + wave * 32 + pl;          // j index within pair row
    const float* ojr = ojc + ((size_t)b * LSEQ + p) * 64;
    const float* oir = oic + (size_t)row * 64;
    float* prp = pair + ((size_t)row * LSEQ + p) * 64;

    float v[32];
#pragma unroll
    for (int s = 0; s < 4; ++s) {
        int k0 = 16 * s + 8 * hq;
#pragma unroll
        for (int j = 0; j < 8; ++j) v[8 * s + j] = ojr[k0 + j] + oir[k0 + j];
    }
    float ss = 0.0f;
#pragma unroll
    for (int i = 0; i < 32; ++i) ss = fmaf(v[i], v[i], ss);
    ss += __shfl_xor(ss, 32);
    float rs = rsqrtf(ss * (1.0f / PDIM) + 1e-5f);
    bf16x8 zh[4], zl[4];
#pragma unroll
    for (int s = 0; s < 4; ++s)
#pragma unroll
        for (int j = 0; j < 8; ++j) {
            unsigned short h, l;
            split_bf(v[8 * s + j] * rs, h, l);
            zh[s][j] = (short)h; zl[s][j] = (short)l;
        }

    f32x16 acc0, acc1;
#pragma unroll
    for (int r = 0; r < 16; ++r) {
        int rr = (r & 3) + 8 * (r >> 2) + 4 * hq;
        acc0[r] = b1p[rr];
        acc1[r] = b1p[32 + rr];
    }
#pragma unroll
    for (int s = 0; s < 4; ++s) {
        int ko = 16 * s + 8 * hq;
        bf16x8 a0h = *(const bf16x8*)(w1hT + (pl << 6) + ko);
        bf16x8 a0l = *(const bf16x8*)(w1lT + (pl << 6) + ko);
        bf16x8 a1h = *(const bf16x8*)(w1hT + ((32 + pl) << 6) + ko);
        bf16x8 a1l = *(const bf16x8*)(w1lT + ((32 + pl) << 6) + ko);
        acc0 = MFMA32(a0h, zh[s], acc0);
        acc0 = MFMA32(a0h, zl[s], acc0);
        acc0 = MFMA32(a0l, zh[s], acc0);
        acc1 = MFMA32(a1h, zh[s], acc1);
        acc1 = MFMA32(a1h, zl[s], acc1);
        acc1 = MFMA32(a1l, zh[s], acc1);
    }
    float u0[16], u1[16];
#pragma unroll
    for (int r = 0; r < 16; ++r) { u0[r] = gelu_erf(acc0[r]); u1[r] = gelu_erf(acc1[r]); }

    float rA0[4], rB0[4], rA1[4], rB1[4];
#pragma unroll
    for (int i = 0; i < 4; ++i) {
        rA0[i] = __shfl_xor(hq ? u0[i] : u0[4 + i], 32);
        rB0[i] = __shfl_xor(hq ? u0[8 + i] : u0[12 + i], 32);
        rA1[i] = __shfl_xor(hq ? u1[i] : u1[4 + i], 32);
        rB1[i] = __shfl_xor(hq ? u1[8 + i] : u1[12 + i], 32);
    }
    bf16x8 uh[4], ul[4];
#pragma unroll
    for (int s = 0; s < 4; ++s) {
        int tt = s >> 1, q = s & 1;
#pragma unroll
        for (int i = 0; i < 4; ++i) {
            float own_f = q ? (tt ? u1[8 + i] : u0[8 + i]) : (tt ? u1[i] : u0[i]);
            float own_s = q ? (tt ? u1[12 + i] : u0[12 + i]) : (tt ? u1[4 + i] : u0[4 + i]);
            float rcv   = q ? (tt ? rB1[i] : rB0[i]) : (tt ? rA1[i] : rA0[i]);
            float f  = hq ? rcv : own_f;
            float g2 = hq ? own_s : rcv;
            unsigned short h, l;
            split_bf(f, h, l);  uh[s][i] = (short)h;     ul[s][i] = (short)l;
            split_bf(g2, h, l); uh[s][4 + i] = (short)h; ul[s][4 + i] = (short)l;
        }
    }

    f32x16 c0, c1;
#pragma unroll
    for (int r = 0; r < 16; ++r) {
        int rr = (r & 3) + 8 * (r >> 2) + 4 * hq;
        c0[r] = b2[rr] + prp[rr];
        c1[r] = b2[32 + rr] + prp[32 + rr];
    }
#pragma unroll
    for (int s = 0; s < 4; ++s) {
        int ko = 16 * s + 8 * hq;
        bf16x8 a0h = *(const bf16x8*)(w2hT + (pl << 6) + ko);
        bf16x8 a0l = *(const bf16x8*)(w2lT + (pl << 6) + ko);
        bf16x8 a1h = *(const bf16x8*)(w2hT + ((32 + pl) << 6) + ko);
        bf16x8 a1l = *(const bf16x8*)(w2lT + ((32 + pl) << 6) + ko);
        c0 = MFMA32(a0h, uh[s], c0);
        c0 = MFMA32(a0h, ul[s], c0);
        c0 = MFMA32(a0l, uh[s], c0);
        c1 = MFMA32(a1h, uh[s], c1);
        c1 = MFMA32(a1h, ul[s], c1);
        c1 = MFMA32(a1l, uh[s], c1);
    }
#pragma unroll
    for (int r = 0; r < 16; ++r) {
        int rr = (r & 3) + 8 * (r >> 2) + 4 * hq;
        prp[rr] = c0[r];
        prp[32 + rr] = c1[r];
    }
}

// ============ MFMA distogram head ============
__global__ void __launch_bounds__(256) k_dist(
    const float* __restrict__ pair,
    const unsigned short* __restrict__ w1hT, const unsigned short* __restrict__ w1lT,
    const float* __restrict__ b1p,
    const unsigned short* __restrict__ w2hT, const unsigned short* __restrict__ w2lT,
    const float* __restrict__ w2c, const float* __restrict__ b2,
    float* __restrict__ out) {
    int blk = blockIdx.x;
    int row = blk / 3, seg = blk % 3;
    int t = threadIdx.x;
    int wave = t >> 6, lane = t & 63;
    int pl = lane & 31, hq = lane >> 5;
    int p = seg * 128 + wave * 32 + pl;
    const float* prp = pair + ((size_t)row * LSEQ + p) * 64;
    float v[32];
#pragma unroll
    for (int s = 0; s < 4; ++s) {
        int k0 = 16 * s + 8 * hq;
#pragma unroll
        for (int j = 0; j < 8; ++j) v[8 * s + j] = prp[k0 + j];
    }
    float sm = 0.0f;
#pragma unroll
    for (int i = 0; i < 32; ++i) sm += v[i];
    sm += __shfl_xor(sm, 32);
    float mean = sm * (1.0f / PDIM);
    float ss = 0.0f;
#pragma unroll
    for (int i = 0; i < 32; ++i) { v[i] -= mean; ss = fmaf(v[i], v[i], ss); }
    ss += __shfl_xor(ss, 32);
    float rs = rsqrtf(ss * (1.0f / PDIM) + 1e-5f);
    bf16x8 zh[4], zl[4];
#pragma unroll
    for (int s = 0; s < 4; ++s)
#pragma unroll
        for (int j = 0; j < 8; ++j) {
            unsigned short h, l;
            split_bf(v[8 * s + j] * rs, h, l);
            zh[s][j] = (short)h; zl[s][j] = (short)l;
        }
    f32x16 acc0, acc1;
#pragma unroll
    for (int r = 0; r < 16; ++r) {
        int rr = (r & 3) + 8 * (r >> 2) + 4 * hq;
        acc0[r] = b1p[rr];
        acc1[r] = b1p[32 + rr];
    }
#pragma unroll
    for (int s = 0; s < 4; ++s) {
        int ko = 16 * s + 8 * hq;
        bf16x8 a0h = *(const bf16x8*)(w1hT + (pl << 6) + ko);
        bf16x8 a0l = *(const bf16x8*)(w1lT + (pl << 6) + ko);
        bf16x8 a1h = *(const bf16x8*)(w1hT + ((32 + pl) << 6) + ko);
        bf16x8 a1l = *(const bf16x8*)(w1lT + ((32 + pl) << 6) + ko);
        acc0 = MFMA32(a0h, zh[s], acc0);
        acc0 = MFMA32(a0h, zl[s], acc0);
        acc0 = MFMA32(a0l, zh[s], acc0);
        acc1 = MFMA32(a1h, zh[s], acc1);
        acc1 = MFMA32(a1h, zl[s], acc1);
        acc1 = MFMA32(a1l, zh[s], acc1);
    }
    float u0[16], u1[16];
    float p64 = 0.0f;
#pragma unroll
    for (int r = 0; r < 16; ++r) {
        int rr = (r & 3) + 8 * (r >> 2) + 4 * hq;
        u0[r] = gelu_erf(acc0[r]);
        u1[r] = gelu_erf(acc1[r]);
        p64 = fmaf(u0[r], w2c[rr], p64);
        p64 = fmaf(u1[r], w2c[32 + rr], p64);
    }
    p64 += __shfl_xor(p64, 32);
    float rA0[4], rB0[4], rA1[4], rB1[4];
#pragma unroll
    for (int i = 0; i < 4; ++i) {
        rA0[i] = __shfl_xor(hq ? u0[i] : u0[4 + i], 32);
        rB0[i] = __shfl_xor(hq ? u0[8 + i] : u0[12 + i], 32);
        rA1[i] = __shfl_xor(hq ? u1[i] : u1[4 + i], 32);
        rB1[i] = __shfl_xor(hq ? u1[8 + i] : u1[12 + i], 32);
    }
    bf16x8 uh[4], ul[4];
#pragma unroll
    for (int s = 0; s < 4; ++s) {
        int tt = s >> 1, q = s & 1;
#pragma unroll
        for (int i = 0; i < 4; ++i) {
            float own_f = q ? (tt ? u1[8 + i] : u0[8 + i]) : (tt ? u1[i] : u0[i]);
            float own_s = q ? (tt ? u1[12 + i] : u0[12 + i]) : (tt ? u1[4 + i] : u0[4 + i]);
            float rcv   = q ? (tt ? rB1[i] : rB0[i]) : (tt ? rA1[i] : rA0[i]);
            float f  = hq ? rcv : own_f;
            float g2 = hq ? own_s : rcv;
            unsigned short h, l;
            split_bf(f, h, l);  uh[s][i] = (short)h;     ul[s][i] = (short)l;
            split_bf(g2, h, l); uh[s][4 + i] = (short)h; ul[s][4 + i] = (short)l;
        }
    }
    f32x16 c0, c1;
#pragma unroll
    for (int r = 0; r < 16; ++r) {
        int rr = (r & 3) + 8 * (r >> 2) + 4 * hq;
        c0[r] = b2[rr];
        c1[r] = b2[32 + rr];
    }
#pragma unroll
    for (int s = 0; s < 4; ++s) {
        int ko = 16 * s + 8 * hq;
        bf16x8 a0h = *(const bf16x8*)(w2hT + (pl << 6) + ko);
        bf16x8 a0l = *(const bf16x8*)(w2lT + (pl << 6) + ko);
        bf16x8 a1h = *(const bf16x8*)(w2hT + ((32 + pl) << 6) + ko);
        bf16x8 a1l = *(const bf16x8*)(w2lT + ((32 + pl) << 6) + ko);
        c0 = MFMA32(a0h, uh[s], c0);
        c0 = MFMA32(a0h, ul[s], c0);
        c0 = MFMA32(a0l, uh[s], c0);
        c1 = MFMA32(a1h, uh[s], c1);
        c1 = MFMA32(a1h, ul[s], c1);
        c1 = MFMA32(a1l, uh[s], c1);
    }
    float* orow = out + ((size_t)row * LSEQ + p) * NBINS;
#pragma unroll
    for (int r = 0; r < 16; ++r) {
        int rr = (r & 3) + 8 * (r >> 2) + 4 * hq;
        orow[rr] = c0[r];
        orow[32 + rr] = c1[r];
    }
    if (hq == 0) orow[64] = p64 + b2[64];
}

// out = (out + out^T(1,2)) / 2, in place
__global__ void k_sym(float* __restrict__ out) {
    int row = blockIdx.x;            // b*L + l
    int b = row / LSEQ, l = row % LSEQ;
    int t = threadIdx.x;
    float* obp = out + (size_t)b * LSEQ * LSEQ * NBINS;
    int tot = (LSEQ - l) * NBINS;
    for (int n = t; n < tot; n += 256) {
        int m = l + n / NBINS;
        int k = n % NBINS;
        size_t i1 = ((size_t)l * LSEQ + m) * NBINS + k;
        size_t i2 = ((size_t)m * LSEQ + l) * NBINS + k;
        float a = obp[i1], c = obp[i2];
        float vv = 0.5f * (a + c);
        obp[i1] = vv;
        obp[i2] = vv;
    }
}

extern "C" void kernel_launch(void* const* d_in, const int* in_sizes, int n_in,
                              void* d_out, int out_size, void* d_ws, size_t ws_size,
                              hipStream_t stream) {
    const float* x        = (const float*)d_in[0];
    const float* rp_w     = (const float*)d_in[1];
    const float* rp_b     = (const float*)d_in[2];
    const float* pos      = (const float*)d_in[3];
    const float* pii_w    = (const float*)d_in[4];
    const float* pii_b    = (const float*)d_in[5];
    const float* pij_w    = (const float*)d_in[6];
    const float* pij_b    = (const float*)d_in[7];
    const float* rel_emb  = (const float*)d_in[8];
    const float* ln_seq_g = (const float*)d_in[9];
    const float* ln_seq_b = (const float*)d_in[10];
    const float* ln_pair_g= (const float*)d_in[11];
    const float* ln_pair_b= (const float*)d_in[12];
    const float* pb_w     = (const float*)d_in[13];
    const float* in_w     = (const float*)d_in[14];
    const float* in_b     = (const float*)d_in[15];
    const float* out_w    = (const float*)d_in[16];
    const float* out_b    = (const float*)d_in[17];
    const float* ff_ln_g  = (const float*)d_in[18];
    const float* ff_ln_b  = (const float*)d_in[19];
    const float* ff_w1    = (const float*)d_in[20];
    const float* ff_b1    = (const float*)d_in[21];
    const float* ff_w2    = (const float*)d_in[22];
    const float* ff_b2    = (const float*)d_in[23];
    const float* pu_ln_g  = (const float*)d_in[24];
    const float* pu_ln_b  = (const float*)d_in[25];
    const float* pu_w1    = (const float*)d_in[26];
    const float* pu_b1    = (const float*)d_in[27];
    const float* pu_w2    = (const float*)d_in[28];
    const float* pu_b2    = (const float*)d_in[29];
    const float* outer_w  = (const float*)d_in[30];
    const float* outer_b  = (const float*)d_in[31];
    const float* dh_ln_g  = (const float*)d_in[32];
    const float* dh_ln_b  = (const float*)d_in[33];
    const float* dh_w1    = (const float*)d_in[34];
    const float* dh_b1    = (const float*)d_in[35];
    const float* dh_w2    = (const float*)d_in[36];
    const float* dh_b2    = (const float*)d_in[37];
    float* outp = (float*)d_out;

    float* W = (float*)d_ws;
    float* h    = W;  W += BATCH * LSEQ * HD;
    float* sn   = W;  W += BATCH * LSEQ * HD;
    float* qkv  = W;  W += BATCH * LSEQ * 3 * HD;
    float* ob   = W;  W += BATCH * LSEQ * HD;
    float* mid  = W;  W += BATCH * LSEQ * 4 * HD;
    float* mask = W;  W += LSEQ * LSEQ;
    float* poi  = W;  W += BATCH * LSEQ * PDIM;
    float* poj  = W;  W += BATCH * LSEQ * PDIM;
    float* b1p  = W;  W += 5 * 64;
    float* w2c  = W;  W += 64;
    unsigned short* w1hT = (unsigned short*)W;  W += 5 * 2048;
    unsigned short* w1lT = (unsigned short*)W;  W += 5 * 2048;
    unsigned short* w2hT = (unsigned short*)W;  W += 5 * 2048;
    unsigned short* w2lT = (unsigned short*)W;  W += 5 * 2048;
    // seq-GEMM split/transposed weights (bf16 hi/lo), per-layer strides in elems
    unsigned short* qwT_h = (unsigned short*)W;  W += 4 * 196608 / 2;
    unsigned short* qwT_l = (unsigned short*)W;  W += 4 * 196608 / 2;
    unsigned short* owT_h = (unsigned short*)W;  W += 4 * 65536 / 2;
    unsigned short* owT_l = (unsigned short*)W;  W += 4 * 65536 / 2;
    unsigned short* f1T_h = (unsigned short*)W;  W += 4 * 262144 / 2;
    unsigned short* f1T_l = (unsigned short*)W;  W += 4 * 262144 / 2;
    unsigned short* f2T_h = (unsigned short*)W;  W += 4 * 262144 / 2;
    unsigned short* f2T_l = (unsigned short*)W;  W += 4 * 262144 / 2;
    float* pair = W;  W += (size_t)BATCH * LSEQ * LSEQ * PDIM;

    const int rows = BATCH * LSEQ;   // 768

    k_prep<<<5, 64, 0, stream>>>(pu_ln_g, pu_ln_b, pu_w1, pu_b1, pu_w2,
                                 dh_ln_g, dh_ln_b, dh_w1, dh_b1, dh_w2,
                                 w1hT, w1lT, w2hT, w2lT, b1p, w2c);
    k_split_T<<<4 * 4 * 12, 256, 0, stream>>>(in_w,  qwT_h, qwT_l, 256, 768,  4, 12, 196608, 196608);
    k_split_T<<<4 * 4 * 4,  256, 0, stream>>>(out_w, owT_h, owT_l, 256, 256,  4, 4,  65536,  65536);
    k_split_T<<<4 * 4 * 16, 256, 0, stream>>>(ff_w1, f1T_h, f1T_l, 256, 1024, 4, 16, 262144, 262144);
    k_split_T<<<4 * 16 * 4, 256, 0, stream>>>(ff_w2, f2T_h, f2T_l, 1024, 256, 16, 4, 262144, 262144);
    k_h_init<<<rows, 256, 0, stream>>>(x, rp_w, rp_b, pos, h);
    k_proj2<<<rows, 128, 0, stream>>>(h, pii_w, pij_w, pii_b, pij_b, 0, poi, poj);
    k_pair_init<<<rows, 256, 0, stream>>>(poi, poj, rel_emb, pair);

    for (int i = 0; i < 4; ++i) {
        k_ln_seq<<<rows, 256, 0, stream>>>(h, ln_seq_g + i * HD, ln_seq_b + i * HD, sn);
        k_mask<<<LSEQ * LSEQ / 8, 256, 0, stream>>>(pair, ln_pair_g + i * PDIM,
                                                    ln_pair_b + i * PDIM,
                                                    pb_w + i * PDIM * NHEAD, mask);
        // qkv = sn @ in_w + in_b
        k_gemm<false><<<144, 256, 0, stream>>>(sn, qwT_h + i * 196608, qwT_l + i * 196608,
                                               in_b + i * 768, nullptr, qkv, 256, 768);
        k_attn<<<BATCH * NHEAD * LSEQ, 256, 0, stream>>>(qkv, mask, ob);
        // h += ob @ out_w + out_b
        k_gemm<false><<<48, 256, 0, stream>>>(ob, owT_h + i * 65536, owT_l + i * 65536,
                                              out_b + i * 256, h, h, 256, 256);
        k_ln_seq<<<rows, 256, 0, stream>>>(h, ff_ln_g + i * HD, ff_ln_b + i * HD, sn);
        // mid = gelu(sn @ ff_w1 + b1)
        k_gemm<true><<<192, 256, 0, stream>>>(sn, f1T_h + i * 262144, f1T_l + i * 262144,
                                              ff_b1 + i * 1024, nullptr, mid, 256, 1024);
        // h += mid @ ff_w2 + b2
        k_gemm<false><<<48, 256, 0, stream>>>(mid, f2T_h + i * 262144, f2T_l + i * 262144,
                                              ff_b2 + i * 256, h, h, 1024, 256);
        // centered oi+outer_b (poi) and centered oj (poj)
        k_proj2<<<rows, 128, 0, stream>>>(h, outer_w + i * 2 * HD * PDIM,
                                          outer_w + i * 2 * HD * PDIM + HD * PDIM,
                                          outer_b + i * PDIM, nullptr, 1, poi, poj);
        k_pair_upd<<<rows * 3, 256, 0, stream>>>(poj, poi,
                                                 w1hT + i * 4096, w1lT + i * 4096,
                                                 b1p + i * 64,
                                                 w2hT + i * 4096, w2lT + i * 4096,
                                                 pu_b2 + i * PDIM, pair);
    }

    k_dist<<<rows * 3, 256, 0, stream>>>(pair, w1hT + 4 * 4096, w1lT + 4 * 4096,
                                         b1p + 4 * 64, w2hT + 4 * 4096, w2lT + 4 * 4096,
                                         w2c, dh_b2, outp);
    k_sym<<<rows, 256, 0, stream>>>(outp);
}